// Round 11
// baseline (15607.114 us; speedup 1.0000x reference)
//
#include <hip/hip_runtime.h>
#include <cstdint>
#include <cstddef>

// Problem constants (match reference)
#define NN      30000     // nodes
#define NE      250000    // edges (one direction)
#define NQ      150000    // qualifiers
#define DIM     200
#define DH      100       // DIM/2
#define RRR     400       // R
#define RELROWS 801       // 2R+1
#define RELALL  802       // 2R+2 (with loop row)
#define ALPHA_C 0.8f
#define BN_EPS_C 1e-5f

// ---------------------------------------------------------------------------
// CSR build helpers
// ---------------------------------------------------------------------------
__global__ void hist_kernel(const int* __restrict__ idx, int n, int* __restrict__ cnt) {
    int i = blockIdx.x * blockDim.x + threadIdx.x;
    if (i < n) atomicAdd(&cnt[idx[i]], 1);
}

// ---- two-level exclusive scan (out has n+1 entries, out[n] = total) ----
#define SC_BLK 256
#define SC_PER 16
#define SC_TILE (SC_BLK * SC_PER)   // 4096

__global__ __launch_bounds__(SC_BLK) void scan_blocks_kernel(
    const int* __restrict__ in, int n, int* __restrict__ out, int* __restrict__ partials)
{
    __shared__ int sh[SC_BLK];
    int b = blockIdx.x, tid = threadIdx.x;
    long base = (long)b * SC_TILE + (long)tid * SC_PER;
    int loc[SC_PER];
    int s = 0;
    #pragma unroll
    for (int j = 0; j < SC_PER; ++j) {
        long idx = base + j;
        int v = (idx < n) ? in[idx] : 0;
        loc[j] = s; s += v;
    }
    sh[tid] = s;
    __syncthreads();
    for (int o = 1; o < SC_BLK; o <<= 1) {
        int t = (tid >= o) ? sh[tid - o] : 0;
        __syncthreads();
        sh[tid] += t;
        __syncthreads();
    }
    int excl = sh[tid] - s;
    #pragma unroll
    for (int j = 0; j < SC_PER; ++j) {
        long idx = base + j;
        if (idx < n) out[idx] = excl + loc[j];
    }
    if (tid == SC_BLK - 1) partials[b] = sh[tid];
}

__global__ __launch_bounds__(1024) void scan_partials_kernel(
    int* __restrict__ partials, int np, int* __restrict__ out_total)
{
    __shared__ int sh[1024];
    int tid = threadIdx.x;
    int v = (tid < np) ? partials[tid] : 0;
    sh[tid] = v;
    __syncthreads();
    for (int o = 1; o < 1024; o <<= 1) {
        int t = (tid >= o) ? sh[tid - o] : 0;
        __syncthreads();
        sh[tid] += t;
        __syncthreads();
    }
    if (tid < np) partials[tid] = sh[tid] - v;   // exclusive
    if (tid == 1023) out_total[0] = sh[1023];    // total -> out[n]
}

__global__ __launch_bounds__(SC_BLK) void scan_add_kernel(
    int* __restrict__ out, int n, const int* __restrict__ partials)
{
    int b = blockIdx.x;
    int add = partials[b];
    long base = (long)b * SC_TILE + threadIdx.x;
    #pragma unroll
    for (int j = 0; j < SC_PER; ++j) {
        long idx = base + (long)j * SC_BLK;
        if (idx < n) out[idx] += add;
    }
}

static inline void run_exscan(const int* in, int* out, int n, int* partials, hipStream_t s) {
    int nb = (n + SC_TILE - 1) / SC_TILE;
    scan_blocks_kernel<<<nb, SC_BLK, 0, s>>>(in, n, out, partials);
    scan_partials_kernel<<<1, 1024, 0, s>>>(partials, nb, out + n);
    scan_add_kernel<<<nb, SC_BLK, 0, s>>>(out, n, partials);
}

__global__ void scatter_kernel(const int* __restrict__ rows, int* __restrict__ cur,
                               int* __restrict__ list, int n) {
    int i = blockIdx.x * blockDim.x + threadIdx.x;
    if (i < n) {
        int r = rows[i];
        int pos = atomicAdd(&cur[r], 1);
        list[pos] = i;
    }
}

__global__ void dinv_kernel(const int* __restrict__ cnt, float* __restrict__ dinv, int n) {
    int i = blockIdx.x * blockDim.x + threadIdx.x;
    if (i < n) {
        int c = cnt[i];
        dinv[i] = (c > 0) ? 1.0f / sqrtf((float)c) : 0.0f;
    }
}

// compact slot assignment for qualifier-bearing edges
__global__ void assign_kernel(const int* __restrict__ qcnt, int* __restrict__ qidx,
                              int* __restrict__ elist, int* __restrict__ nq) {
    int e = blockIdx.x * blockDim.x + threadIdx.x;
    if (e < NE) {
        if (qcnt[e] > 0) {
            int s = atomicAdd(nq, 1);
            qidx[e] = s;
            elist[s] = e;
        } else {
            qidx[e] = -1;
        }
    }
}

// ---------------------------------------------------------------------------
// Rotation kernels — 256-thread blocks, one item per 64-lane wave (4/block)
// ---------------------------------------------------------------------------
// qsum_c[slot] = sum over qualifiers of edge elist[slot] of rotate(x[qe], rel_all[qr])
__global__ __launch_bounds__(256) void qual_agg_kernel(
    const float* __restrict__ x, const float* __restrict__ rel_all,
    const int* __restrict__ qptr, const int* __restrict__ qlist,
    const int* __restrict__ qrel, const int* __restrict__ qent,
    const int* __restrict__ elist, const int* __restrict__ nq,
    float* __restrict__ qsum_c)
{
    int slot = blockIdx.x * 4 + (threadIdx.x >> 6);
    if (slot >= nq[0]) return;
    int e = elist[slot];
    int lane = threadIdx.x & 63;
    int p0 = lane;
    int p1 = lane + 64;
    bool has1 = (p1 < DH);
    float ar0 = 0.f, ai0 = 0.f, ar1 = 0.f, ai1 = 0.f;
    int s = qptr[e], t = qptr[e + 1];
    for (int i = s; i < t; ++i) {
        int q = qlist[i];
        int ent = qent[q];
        int rel = qrel[q];
        const float* xr = x + (long)ent * DIM;
        const float* rp = rel_all + (long)rel * DIM;
        {
            float hr = xr[p0], hi = xr[p0 + DH];
            float rr = rp[p0], ri = rp[p0 + DH];
            ar0 += hr * rr - hi * ri;
            ai0 += hr * ri + hi * rr;
        }
        if (has1) {
            float hr = xr[p1], hi = xr[p1 + DH];
            float rr = rp[p1], ri = rp[p1 + DH];
            ar1 += hr * rr - hi * ri;
            ai1 += hr * ri + hi * rr;
        }
    }
    float* o = qsum_c + (long)slot * DIM;
    o[p0] = ar0; o[p0 + DH] = ai0;
    if (has1) { o[p1] = ar1; o[p1 + DH] = ai1; }
}

// out[row, col_off..col_off+200) = sum over CSR edges of
//   rotate(x[col], alpha*rel_all[etype+off] + q_edge_c[qidx[e]]) * norm
__global__ __launch_bounds__(256) void edge_agg_kernel(
    const float* __restrict__ x, const float* __restrict__ rel_all,
    const float* __restrict__ q_edge_c, const int* __restrict__ qidx,
    const int* __restrict__ ptr, const int* __restrict__ list,
    const int* __restrict__ other, const int* __restrict__ etype,
    const float* __restrict__ dinv, int rel_off,
    float* __restrict__ out, int ldo, int col_off)
{
    int n = blockIdx.x * 4 + (threadIdx.x >> 6);
    if (n >= NN) return;
    int lane = threadIdx.x & 63;
    int p0 = lane;
    int p1 = lane + 64;
    bool has1 = (p1 < DH);
    float ar0 = 0.f, ai0 = 0.f, ar1 = 0.f, ai1 = 0.f;
    int s = ptr[n], e = ptr[n + 1];
    float dn = dinv[n];
    for (int i = s; i < e; ++i) {
        int eid = list[i];
        int col = other[eid];
        int t = etype[eid] + rel_off;
        int qi = qidx[eid];
        float norm = dn * dinv[col];
        const float* xr = x + (long)col * DIM;
        const float* rp = rel_all + (long)t * DIM;
        {
            float hr = xr[p0], hi = xr[p0 + DH];
            float wr = ALPHA_C * rp[p0];
            float wi = ALPHA_C * rp[p0 + DH];
            if (qi >= 0) {
                const float* qp = q_edge_c + (long)qi * DIM;
                wr += qp[p0]; wi += qp[p0 + DH];
            }
            ar0 += (hr * wr - hi * wi) * norm;
            ai0 += (hr * wi + hi * wr) * norm;
        }
        if (has1) {
            float hr = xr[p1], hi = xr[p1 + DH];
            float wr = ALPHA_C * rp[p1];
            float wi = ALPHA_C * rp[p1 + DH];
            if (qi >= 0) {
                const float* qp = q_edge_c + (long)qi * DIM;
                wr += qp[p1]; wi += qp[p1 + DH];
            }
            ar1 += (hr * wr - hi * wi) * norm;
            ai1 += (hr * wi + hi * wr) * norm;
        }
    }
    float* o = out + (long)n * ldo + col_off;
    o[p0] = ar0; o[p0 + DH] = ai0;
    if (has1) { o[p1] = ar1; o[p1 + DH] = ai1; }
}

// out[n, col_off..+200) = rotate(x[n], rel_all[last])
__global__ __launch_bounds__(256) void rot_loop_kernel(
    const float* __restrict__ x, const float* __restrict__ rel_all,
    float* __restrict__ out, int ldo, int col_off)
{
    int n = blockIdx.x * 4 + (threadIdx.x >> 6);
    if (n >= NN) return;
    int lane = threadIdx.x & 63;
    const float* rp = rel_all + (long)(RELALL - 1) * DIM;
    const float* xr = x + (long)n * DIM;
    float* o = out + (long)n * ldo + col_off;
    {
        float hr = xr[lane], hi = xr[lane + DH];
        float rr = rp[lane], ri = rp[lane + DH];
        o[lane] = hr * rr - hi * ri;
        o[lane + DH] = hr * ri + hi * rr;
    }
    int p1 = lane + 64;
    if (p1 < DH) {
        float hr = xr[p1], hi = xr[p1 + DH];
        float rr = rp[p1], ri = rp[p1 + DH];
        o[p1] = hr * rr - hi * ri;
        o[p1 + DH] = hr * ri + hi * rr;
    }
}

// zero-fill kernel (used for clean-fail path)
__global__ void zero_kernel(float* __restrict__ p, long n) {
    long i = (long)blockIdx.x * blockDim.x + threadIdx.x;
    if (i < n) p[i] = 0.f;
}

// ---------------------------------------------------------------------------
// GEMM: C(M,N) = scale*(A(M,K) @ B) [+bias] [relu] [+=C]
// B is (K,N) row-major, or (N,K) row-major if TRANSB.
// 128x128 tile, 256 threads, 8x8 microtile split 4+4 at offset 64 (2-way-max
// LDS bank conflicts). SINGLE-buffer LDS (16.9 KB) + register prefetch of the
// next K-tile issued before compute (global latency hidden under 1024 FMAs),
// __launch_bounds__(256,4) pins VGPR <=128 for 4 waves/SIMD (round-10 lesson:
// dbuf's 188 VGPR / 33.8 KB LDS halved occupancy and lost 45%).
// If Mdev != nullptr, effective M is read from device (<= M).
// ---------------------------------------------------------------------------
#define BM 128
#define BN 128
#define BK 16

template <bool TRANSB>
__global__ __launch_bounds__(256, 4) void gemm_kernel(
    const float* __restrict__ A, const float* __restrict__ B, float* __restrict__ C,
    int M, int K, int Ncols, int ldc,
    float scale, const float* __restrict__ bias, int relu, int acc,
    const int* __restrict__ Mdev)
{
    int Meff = Mdev ? Mdev[0] : M;
    int row0 = blockIdx.y * BM;
    if (row0 >= Meff) return;
    int col0 = blockIdx.x * BN;
    __shared__ float As[BK][BM + 4];
    __shared__ float Bs[BK][BN + 4];
    int tid = threadIdx.x;
    int tm = tid >> 4;      // 0..15 -> rows {tm*4+i, 64+tm*4+i}
    int tn = tid & 15;      // 0..15 -> cols {tn*4+j, 64+tn*4+j}
    float accv[8][8] = {{0.f}};
    int ktiles = (K + BK - 1) / BK;

    float4 ra[2], rb[2];

    // --- staging loads: global -> regs (tile kt) ---
    auto loadA = [&](int kt) {
        int k0 = kt * BK;
        #pragma unroll
        for (int i = 0; i < 2; ++i) {
            int f4 = tid + i * 256;           // 0..511
            int m  = f4 >> 2;                 // 0..127
            int kq = (f4 & 3) * 4;            // 0,4,8,12
            int gm = row0 + m, gk = k0 + kq;
            float4 v = make_float4(0.f, 0.f, 0.f, 0.f);
            if (gm < Meff) {
                if (gk + 3 < K) {
                    v = *reinterpret_cast<const float4*>(A + (long)gm * K + gk);
                } else {
                    float t0[4] = {0.f, 0.f, 0.f, 0.f};
                    #pragma unroll
                    for (int j = 0; j < 4; ++j) if (gk + j < K) t0[j] = A[(long)gm * K + gk + j];
                    v = make_float4(t0[0], t0[1], t0[2], t0[3]);
                }
            }
            ra[i] = v;
        }
    };
    auto loadB = [&](int kt) {
        int k0 = kt * BK;
        if (!TRANSB) {
            #pragma unroll
            for (int i = 0; i < 2; ++i) {
                int f4 = tid + i * 256;       // 0..511
                int k  = f4 >> 5;             // 0..15
                int n4 = (f4 & 31) * 4;       // 0..124
                int gk = k0 + k, gn = col0 + n4;
                float4 v = make_float4(0.f, 0.f, 0.f, 0.f);
                if (gk < K) {
                    if (gn + 3 < Ncols) {
                        v = *reinterpret_cast<const float4*>(B + (long)gk * Ncols + gn);
                    } else {
                        float t0[4] = {0.f, 0.f, 0.f, 0.f};
                        #pragma unroll
                        for (int j = 0; j < 4; ++j) if (gn + j < Ncols) t0[j] = B[(long)gk * Ncols + gn + j];
                        v = make_float4(t0[0], t0[1], t0[2], t0[3]);
                    }
                }
                rb[i] = v;
            }
        } else {
            #pragma unroll
            for (int i = 0; i < 2; ++i) {
                int f4 = tid + i * 256;       // 0..511
                int n  = f4 >> 2;             // 0..127
                int kq = (f4 & 3) * 4;        // 0,4,8,12
                int gn = col0 + n, gk = k0 + kq;
                float4 v = make_float4(0.f, 0.f, 0.f, 0.f);
                if (gn < Ncols) {
                    if (gk + 3 < K) {
                        v = *reinterpret_cast<const float4*>(B + (long)gn * K + gk);
                    } else {
                        float t0[4] = {0.f, 0.f, 0.f, 0.f};
                        #pragma unroll
                        for (int j = 0; j < 4; ++j) if (gk + j < K) t0[j] = B[(long)gn * K + gk + j];
                        v = make_float4(t0[0], t0[1], t0[2], t0[3]);
                    }
                }
                rb[i] = v;
            }
        }
    };
    auto storeA = [&]() {
        #pragma unroll
        for (int i = 0; i < 2; ++i) {
            int f4 = tid + i * 256;
            int m  = f4 >> 2;
            int kq = (f4 & 3) * 4;
            As[kq + 0][m] = ra[i].x; As[kq + 1][m] = ra[i].y;
            As[kq + 2][m] = ra[i].z; As[kq + 3][m] = ra[i].w;
        }
    };
    auto storeB = [&]() {
        if (!TRANSB) {
            #pragma unroll
            for (int i = 0; i < 2; ++i) {
                int f4 = tid + i * 256;
                int k  = f4 >> 5;
                int n4 = (f4 & 31) * 4;
                Bs[k][n4 + 0] = rb[i].x; Bs[k][n4 + 1] = rb[i].y;
                Bs[k][n4 + 2] = rb[i].z; Bs[k][n4 + 3] = rb[i].w;
            }
        } else {
            #pragma unroll
            for (int i = 0; i < 2; ++i) {
                int f4 = tid + i * 256;
                int n  = f4 >> 2;
                int kq = (f4 & 3) * 4;
                Bs[kq + 0][n] = rb[i].x; Bs[kq + 1][n] = rb[i].y;
                Bs[kq + 2][n] = rb[i].z; Bs[kq + 3][n] = rb[i].w;
            }
        }
    };

    // prologue: tile 0 -> LDS
    loadA(0); loadB(0);
    storeA(); storeB();

    for (int kt = 0; kt < ktiles; ++kt) {
        __syncthreads();                           // tile kt's LDS writes visible
        bool more = (kt + 1 < ktiles);
        if (more) { loadA(kt + 1); loadB(kt + 1); }  // issue next-tile global loads
        #pragma unroll
        for (int k = 0; k < BK; ++k) {             // 1024 FMAs hide the load latency
            float a[8], b[8];
            *reinterpret_cast<float4*>(&a[0]) = *reinterpret_cast<const float4*>(&As[k][tm * 4]);
            *reinterpret_cast<float4*>(&a[4]) = *reinterpret_cast<const float4*>(&As[k][64 + tm * 4]);
            *reinterpret_cast<float4*>(&b[0]) = *reinterpret_cast<const float4*>(&Bs[k][tn * 4]);
            *reinterpret_cast<float4*>(&b[4]) = *reinterpret_cast<const float4*>(&Bs[k][64 + tn * 4]);
            #pragma unroll
            for (int i = 0; i < 8; ++i)
                #pragma unroll
                for (int j = 0; j < 8; ++j)
                    accv[i][j] += a[i] * b[j];
        }
        __syncthreads();                           // all reads of tile kt done
        if (more) { storeA(); storeB(); }          // overwrite LDS with tile kt+1
    }

    #pragma unroll
    for (int i = 0; i < 8; ++i) {
        int gm = row0 + ((i < 4) ? (tm * 4 + i) : (64 + tm * 4 + (i - 4)));
        if (gm >= Meff) continue;
        #pragma unroll
        for (int j = 0; j < 8; ++j) {
            int gn = col0 + ((j < 4) ? (tn * 4 + j) : (64 + tn * 4 + (j - 4)));
            if (gn >= Ncols) continue;
            float v = accv[i][j] * scale;
            if (bias) v += bias[gn];
            if (relu) v = fmaxf(v, 0.f);
            long off = (long)gm * ldc + gn;
            if (acc) v += C[off];
            C[off] = v;
        }
    }
}

// ---------------------------------------------------------------------------
// BatchNorm pieces (column-wise over NN rows)
// ---------------------------------------------------------------------------
__global__ __launch_bounds__(256) void bn_stats_kernel(
    const float* __restrict__ in, float scale, int relu_in,
    float* __restrict__ s1, float* __restrict__ s2)
{
    int d = threadIdx.x;
    if (d >= DIM) return;
    float a = 0.f, b = 0.f;
    for (int r = blockIdx.x; r < NN; r += gridDim.x) {
        float v = in[(long)r * DIM + d] * scale;
        if (relu_in) v = fmaxf(v, 0.f);
        a += v;
        b += v * v;
    }
    atomicAdd(&s1[d], a);
    atomicAdd(&s2[d], b);
}

__global__ void bn_finalize_kernel(
    const float* __restrict__ s1, const float* __restrict__ s2,
    const float* __restrict__ g, const float* __restrict__ be,
    float* __restrict__ aa, float* __restrict__ cc)
{
    int d = threadIdx.x;
    if (d >= DIM) return;
    float mu = s1[d] / (float)NN;
    float var = s2[d] / (float)NN - mu * mu;
    float inv = 1.0f / sqrtf(var + BN_EPS_C);
    float a = g[d] * inv;
    aa[d] = a;
    cc[d] = be[d] - mu * a;
}

__global__ __launch_bounds__(256) void bn_apply_kernel(
    const float* __restrict__ in, float scale, int relu_in,
    const float* __restrict__ aa, const float* __restrict__ cc, int relu_out,
    float* __restrict__ out, int ldo, int col0)
{
    int d = threadIdx.x;
    if (d >= DIM) return;
    int r = blockIdx.x;
    float v = in[(long)r * DIM + d] * scale;
    if (relu_in) v = fmaxf(v, 0.f);
    v = aa[d] * v + cc[d];
    if (relu_out) v = fmaxf(v, 0.f);
    out[(long)r * ldo + col0 + d] = v;
}

// ---------------------------------------------------------------------------
// LRGA pieces
// ---------------------------------------------------------------------------
__global__ __launch_bounds__(128) void colsum_uv_kernel(
    const float* __restrict__ t, float* __restrict__ cs)
{
    int d = threadIdx.x;
    if (d >= 100) return;
    float s = 0.f;
    for (int r = blockIdx.x; r < NN; r += gridDim.x) s += t[(long)r * DIM + d];
    atomicAdd(&cs[d], s);
}

__global__ void nf_kernel(const float* __restrict__ cs, float* __restrict__ nf) {
    int lane = threadIdx.x;
    float v = (lane < 50) ? cs[lane] * cs[50 + lane] : 0.f;
    for (int off = 32; off > 0; off >>= 1) v += __shfl_down(v, off);
    if (lane == 0) nf[0] = v / (float)NN + 1e-6f;
}

__global__ __launch_bounds__(256) void vtz_kernel(
    const float* __restrict__ t, float* __restrict__ M50)
{
    __shared__ float vz[100];
    int tid = threadIdx.x;
    float acc[10];
    #pragma unroll
    for (int a = 0; a < 10; ++a) acc[a] = 0.f;
    for (int r = blockIdx.x; r < NN; r += gridDim.x) {
        if (tid < 100) vz[tid] = t[(long)r * DIM + 50 + tid];
        __syncthreads();
        #pragma unroll
        for (int a = 0; a < 10; ++a) {
            int p = tid + a * 256;
            if (p < 2500) {
                int i = p / 50, j = p % 50;
                acc[a] += vz[i] * vz[50 + j];
            }
        }
        __syncthreads();
    }
    #pragma unroll
    for (int a = 0; a < 10; ++a) {
        int p = tid + a * 256;
        if (p < 2500) atomicAdd(&M50[p], acc[a]);
    }
}

__global__ __launch_bounds__(256) void um_kernel(
    const float* __restrict__ t, const float* __restrict__ M50,
    const float* __restrict__ nf, float* __restrict__ cat)
{
    __shared__ float Ms[2500];
    int tid = threadIdx.x;
    for (int i = tid; i < 2500; i += 256) Ms[i] = M50[i];
    __syncthreads();
    int n = blockIdx.x * 256 + tid;
    if (n >= NN) return;
    float inv = 1.0f / nf[0];
    float acc[50];
    #pragma unroll
    for (int j = 0; j < 50; ++j) acc[j] = 0.f;
    for (int k = 0; k < 50; ++k) {
        float u = t[(long)n * DIM + k];
        #pragma unroll
        for (int j = 0; j < 50; ++j) acc[j] += u * Ms[k * 50 + j];
    }
    #pragma unroll
    for (int j = 0; j < 50; ++j) cat[(long)n * 500 + j] = acc[j] * inv;
}

__global__ __launch_bounds__(256) void copy_cols_kernel(
    const float* __restrict__ src, int lds_, int sc0,
    float* __restrict__ dst, int ldd, int dc0,
    int rows, int cols)
{
    int i = blockIdx.x * blockDim.x + threadIdx.x;
    int total = rows * cols;
    if (i >= total) return;
    int r = i / cols, c = i % cols;
    dst[(long)r * ldd + dc0 + c] = src[(long)r * lds_ + sc0 + c];
}

// ---------------------------------------------------------------------------
static inline void launch_gemm(bool transB, const float* A, const float* B, float* C,
                               int Mmax, int K, int Ncols, int ldc, float scale,
                               const float* bias, int relu, int acc,
                               const int* Mdev, hipStream_t s)
{
    dim3 grid((Ncols + BN - 1) / BN, (Mmax + BM - 1) / BM);
    if (transB)
        gemm_kernel<true><<<grid, 256, 0, s>>>(A, B, C, Mmax, K, Ncols, ldc, scale, bias, relu, acc, Mdev);
    else
        gemm_kernel<false><<<grid, 256, 0, s>>>(A, B, C, Mmax, K, Ncols, ldc, scale, bias, relu, acc, Mdev);
}

extern "C" void kernel_launch(void* const* d_in, const int* in_sizes, int n_in,
                              void* d_out, int out_size, void* d_ws, size_t ws_size,
                              hipStream_t stream)
{
    // inputs
    const int*   edge_index = (const int*)d_in[0];        // (2, NE)
    const int*   ei0        = edge_index;
    const int*   ei1        = edge_index + NE;
    const int*   edge_type  = (const int*)d_in[1];        // (NE,)
    const int*   quals_rel  = (const int*)d_in[2];        // (NQ,)
    const int*   quals_ent  = (const int*)d_in[3];
    const int*   quals_edge = (const int*)d_in[4];
    const float* ent_emb    = (const float*)d_in[5];      // (NN, DIM)
    const float* init_rel   = (const float*)d_in[6];      // (801, DIM)
    const float* loop_rel   = (const float*)d_in[7];      // (2, DIM)
    const float* w_in       = (const float*)d_in[8];      // (2, DIM, DIM)
    const float* w_out      = (const float*)d_in[9];
    const float* w_loop     = (const float*)d_in[10];
    const float* w_rel      = (const float*)d_in[11];
    const float* w_q        = (const float*)d_in[12];
    const float* conv_gamma = (const float*)d_in[13];     // (2, DIM)
    const float* conv_beta  = (const float*)d_in[14];
    const float* lrga_w     = (const float*)d_in[15];     // (2, 200, DIM)
    const float* lrga_b     = (const float*)d_in[16];     // (2, 200)
    const float* dimred_w   = (const float*)d_in[17];     // (2, DIM, 500)
    const float* dimred_b   = (const float*)d_in[18];     // (2, DIM)
    const float* fuse_gamma = (const float*)d_in[19];     // (DIM,)
    const float* fuse_beta  = (const float*)d_in[20];

    float* out_x = (float*)d_out;                          // NN*DIM
    float* out_r = (float*)d_out + (long)NN * DIM;         // 801*DIM

    // ---- workspace carve with lifetime-based aliasing (~249 MB total) ----
    char* wp = (char*)d_ws;
    auto alloc = [&](size_t bytes) -> void* {
        void* p = (void*)wp;
        wp += (bytes + 255) & ~(size_t)255;
        return p;
    };
    // Region A (30e6 floats = 120 MB): qsum_c, then pre3|conv_sum|tbuf
    float* regionA  = (float*)alloc(sizeof(float) * (size_t)NQ * DIM);
    float* qsum_c   = regionA;                       // live: qual_agg -> q_edge GEMM
    float* pre3     = regionA;                       // NN*600, live: edge_agg -> conv GEMM
    float* conv_sum = regionA + (size_t)NN * 600;    // NN*200, live: conv GEMM -> bn_apply
    float* tbuf     = conv_sum + (size_t)NN * DIM;   // NN*200, live: LRGA GEMM -> copy T
    // Region B (30e6 floats = 120 MB): q_edge_c, then cat|hbuf
    float* regionB  = (float*)alloc(sizeof(float) * (size_t)NQ * DIM);
    float* q_edge_c = regionB;                       // live: q GEMM -> edge_agg
    float* cat      = regionB;                       // NN*500, live: bn_apply -> dimred
    float* hbuf     = cat + (size_t)NN * 500;        // NN*200, live: dimred -> fuse BN (L0)
    // x_cur aliases out_x: written end of L0, last read before dimred-L1 overwrites d_out
    float* x_cur    = out_x;
    float* rel_all  = (float*)alloc(sizeof(float) * (size_t)RELALL * DIM);
    float* r_buf    = (float*)alloc(sizeof(float) * (size_t)RELROWS * DIM);
    float* wcat     = (float*)alloc(sizeof(float) * 600 * DIM);
    float* dinv0    = (float*)alloc(sizeof(float) * NN);
    float* dinv1    = (float*)alloc(sizeof(float) * NN);
    float* s1       = (float*)alloc(sizeof(float) * DIM);
    float* s2       = (float*)alloc(sizeof(float) * DIM);
    float* aa       = (float*)alloc(sizeof(float) * DIM);
    float* cc       = (float*)alloc(sizeof(float) * DIM);
    float* csUV     = (float*)alloc(sizeof(float) * 100);
    float* nfv      = (float*)alloc(sizeof(float) * 1);
    float* M50      = (float*)alloc(sizeof(float) * 2500);
    int* cnt0  = (int*)alloc(sizeof(int) * NN);
    int* ptr0  = (int*)alloc(sizeof(int) * (NN + 1));
    int* cur0  = (int*)alloc(sizeof(int) * NN);
    int* list0 = (int*)alloc(sizeof(int) * NE);
    int* cnt1  = (int*)alloc(sizeof(int) * NN);
    int* ptr1  = (int*)alloc(sizeof(int) * (NN + 1));
    int* cur1  = (int*)alloc(sizeof(int) * NN);
    int* list1 = (int*)alloc(sizeof(int) * NE);
    int* qcnt  = (int*)alloc(sizeof(int) * NE);
    int* qptr  = (int*)alloc(sizeof(int) * (NE + 1));
    int* qcur  = (int*)alloc(sizeof(int) * NE);
    int* qlist = (int*)alloc(sizeof(int) * NQ);
    int* qidx  = (int*)alloc(sizeof(int) * NE);
    int* elist = (int*)alloc(sizeof(int) * NQ);
    int* nq    = (int*)alloc(sizeof(int) * 1);
    int* partials = (int*)alloc(sizeof(int) * 1024);

    // ---- workspace-size guard: clean deterministic fail instead of GPU abort ----
    size_t needed = (size_t)(wp - (char*)d_ws);
    if (needed > ws_size) {
        long total_out = (long)out_size;
        zero_kernel<<<(int)((total_out + 255) / 256), 256, 0, stream>>>((float*)d_out, total_out);
        return;
    }

    // ---- CSR build (per call; inputs restored before every timed launch) ----
    hipMemsetAsync(cnt0, 0, sizeof(int) * NN, stream);
    hipMemsetAsync(cnt1, 0, sizeof(int) * NN, stream);
    hipMemsetAsync(qcnt, 0, sizeof(int) * NE, stream);
    hipMemsetAsync(nq, 0, sizeof(int), stream);
    hist_kernel<<<(NE + 255) / 256, 256, 0, stream>>>(ei0, NE, cnt0);
    hist_kernel<<<(NE + 255) / 256, 256, 0, stream>>>(ei1, NE, cnt1);
    hist_kernel<<<(NQ + 255) / 256, 256, 0, stream>>>(quals_edge, NQ, qcnt);
    run_exscan(cnt0, ptr0, NN, partials, stream);
    run_exscan(cnt1, ptr1, NN, partials, stream);
    run_exscan(qcnt, qptr, NE, partials, stream);
    hipMemcpyAsync(cur0, ptr0, sizeof(int) * NN, hipMemcpyDeviceToDevice, stream);
    hipMemcpyAsync(cur1, ptr1, sizeof(int) * NN, hipMemcpyDeviceToDevice, stream);
    hipMemcpyAsync(qcur, qptr, sizeof(int) * NE, hipMemcpyDeviceToDevice, stream);
    scatter_kernel<<<(NE + 255) / 256, 256, 0, stream>>>(ei0, cur0, list0, NE);
    scatter_kernel<<<(NE + 255) / 256, 256, 0, stream>>>(ei1, cur1, list1, NE);
    scatter_kernel<<<(NQ + 255) / 256, 256, 0, stream>>>(quals_edge, qcur, qlist, NQ);
    dinv_kernel<<<(NN + 255) / 256, 256, 0, stream>>>(cnt0, dinv0, NN);
    dinv_kernel<<<(NN + 255) / 256, 256, 0, stream>>>(cnt1, dinv1, NN);
    assign_kernel<<<(NE + 255) / 256, 256, 0, stream>>>(qcnt, qidx, elist, nq);

    // ---- layer loop (L=2) ----
    for (int i = 0; i < 2; ++i) {
        const float* xin  = (i == 0) ? ent_emb : x_cur;
        const float* rsrc = (i == 0) ? init_rel : r_buf;

        // rel_all = [r ; loop_rel[i]]
        hipMemcpyAsync(rel_all, rsrc, sizeof(float) * RELROWS * DIM,
                       hipMemcpyDeviceToDevice, stream);
        hipMemcpyAsync(rel_all + (long)RELROWS * DIM, loop_rel + (long)i * DIM,
                       sizeof(float) * DIM, hipMemcpyDeviceToDevice, stream);

        // qualifier aggregation into compact rows (shared by both directions)
        qual_agg_kernel<<<(NQ + 3) / 4, 256, 0, stream>>>(xin, rel_all, qptr, qlist,
                                               quals_rel, quals_ent, elist, nq, qsum_c);
        // q_edge_c = (1-alpha) * qsum_c @ w_q[i]   (dynamic M = *nq)
        launch_gemm(false, qsum_c, w_q + (long)i * DIM * DIM, q_edge_c,
                    NQ, DIM, DIM, DIM, 1.0f - ALPHA_C, nullptr, 0, 0, nq, stream);

        // per-direction aggregation into pre3 columns [0:200 | 200:400 | 400:600]
        // (pre3 overwrites qsum_c region - qsum dead after the GEMM above)
        edge_agg_kernel<<<(NN + 3) / 4, 256, 0, stream>>>(xin, rel_all, q_edge_c, qidx,
                                               ptr0, list0, ei1, edge_type, dinv0, 0,
                                               pre3, 600, 0);
        edge_agg_kernel<<<(NN + 3) / 4, 256, 0, stream>>>(xin, rel_all, q_edge_c, qidx,
                                               ptr1, list1, ei0, edge_type, dinv1, RRR,
                                               pre3, 600, 200);
        rot_loop_kernel<<<(NN + 3) / 4, 256, 0, stream>>>(xin, rel_all, pre3, 600, 400);

        // stacked conv weights: wcat = [w_in; w_out; w_loop] (600 x 200)
        hipMemcpyAsync(wcat,                 w_in   + (long)i * DIM * DIM, sizeof(float) * DIM * DIM, hipMemcpyDeviceToDevice, stream);
        hipMemcpyAsync(wcat + DIM * DIM,     w_out  + (long)i * DIM * DIM, sizeof(float) * DIM * DIM, hipMemcpyDeviceToDevice, stream);
        hipMemcpyAsync(wcat + 2 * DIM * DIM, w_loop + (long)i * DIM * DIM, sizeof(float) * DIM * DIM, hipMemcpyDeviceToDevice, stream);
        // conv_sum = pre3 @ wcat  (single K=600 GEMM)
        launch_gemm(false, pre3, wcat, conv_sum, NN, 600, DIM, DIM, 1.f, nullptr, 0, 0, nullptr, stream);

        // conv BN on conv_sum/3, relu -> x_local into cat[:,100:300]
        // (cat overwrites q_edge_c region - q_edge dead after edge_agg)
        hipMemsetAsync(s1, 0, sizeof(float) * DIM, stream);
        hipMemsetAsync(s2, 0, sizeof(float) * DIM, stream);
        bn_stats_kernel<<<512, 256, 0, stream>>>(conv_sum, 1.0f / 3.0f, 0, s1, s2);
        bn_finalize_kernel<<<1, 256, 0, stream>>>(s1, s2, conv_gamma + (long)i * DIM,
                                                  conv_beta + (long)i * DIM, aa, cc);
        bn_apply_kernel<<<NN, 256, 0, stream>>>(conv_sum, 1.0f / 3.0f, 0, aa, cc, 1,
                                                cat, 500, 100);

        // LRGA on xin: t = relu(x @ lrga_w.T + lrga_b)  (tbuf in regionA tail - safe)
        launch_gemm(true, xin, lrga_w + (long)i * 200 * DIM, tbuf,
                    NN, DIM, 200, 200, 1.f, lrga_b + (long)i * 200, 1, 0, nullptr, stream);
        hipMemsetAsync(csUV, 0, sizeof(float) * 100, stream);
        hipMemsetAsync(M50, 0, sizeof(float) * 2500, stream);
        colsum_uv_kernel<<<256, 128, 0, stream>>>(tbuf, csUV);
        nf_kernel<<<1, 64, 0, stream>>>(csUV, nfv);
        vtz_kernel<<<128, 256, 0, stream>>>(tbuf, M50);
        um_kernel<<<(NN + 255) / 256, 256, 0, stream>>>(tbuf, M50, nfv, cat);
        // cat[:,50:100] = T = t[:,150:200]
        copy_cols_kernel<<<(NN * 50 + 255) / 256, 256, 0, stream>>>(
            tbuf, DIM, 150, cat, 500, 50, NN, 50);
        // cat[:,300:500] = x
        copy_cols_kernel<<<(NN * DIM + 255) / 256, 256, 0, stream>>>(
            xin, DIM, 0, cat, 500, 300, NN, DIM);

        // dimred: h = cat @ dimred_w[i].T + dimred_b[i]
        float* hdst = (i == 0) ? hbuf : out_x;
        launch_gemm(true, cat, dimred_w + (long)i * DIM * 500, hdst,
                    NN, 500, DIM, DIM, 1.f, dimred_b + (long)i * DIM, 0, 0, nullptr, stream);

        if (i == 0) {
            // x = BN(relu(h), fuse_gamma, fuse_beta)  -> x_cur (= out_x scratch)
            hipMemsetAsync(s1, 0, sizeof(float) * DIM, stream);
            hipMemsetAsync(s2, 0, sizeof(float) * DIM, stream);
            bn_stats_kernel<<<512, 256, 0, stream>>>(hdst, 1.0f, 1, s1, s2);
            bn_finalize_kernel<<<1, 256, 0, stream>>>(s1, s2, fuse_gamma, fuse_beta, aa, cc);
            bn_apply_kernel<<<NN, 256, 0, stream>>>(hdst, 1.0f, 1, aa, cc, 0,
                                                    x_cur, DIM, 0);
        }

        // r update: (rel_all @ w_rel[i]) keep rows 0..800
        float* rdst = (i == 0) ? r_buf : out_r;
        launch_gemm(false, rel_all, w_rel + (long)i * DIM * DIM, rdst,
                    RELROWS, DIM, DIM, DIM, 1.f, nullptr, 0, 0, nullptr, stream);
    }
}

// Round 12
// 3151.694 us; speedup vs baseline: 4.9520x; 4.9520x over previous
//
#include <hip/hip_runtime.h>
#include <cstdint>
#include <cstddef>

// Problem constants (match reference)
#define NN      30000     // nodes
#define NE      250000    // edges (one direction)
#define NQ      150000    // qualifiers
#define DIM     200
#define DH      100       // DIM/2
#define RRR     400       // R
#define RELROWS 801       // 2R+1
#define RELALL  802       // 2R+2 (with loop row)
#define ALPHA_C 0.8f
#define BN_EPS_C 1e-5f

// ---------------------------------------------------------------------------
// CSR build helpers
// ---------------------------------------------------------------------------
__global__ void hist_kernel(const int* __restrict__ idx, int n, int* __restrict__ cnt) {
    int i = blockIdx.x * blockDim.x + threadIdx.x;
    if (i < n) atomicAdd(&cnt[idx[i]], 1);
}

// ---- two-level exclusive scan (out has n+1 entries, out[n] = total) ----
#define SC_BLK 256
#define SC_PER 16
#define SC_TILE (SC_BLK * SC_PER)   // 4096

__global__ __launch_bounds__(SC_BLK) void scan_blocks_kernel(
    const int* __restrict__ in, int n, int* __restrict__ out, int* __restrict__ partials)
{
    __shared__ int sh[SC_BLK];
    int b = blockIdx.x, tid = threadIdx.x;
    long base = (long)b * SC_TILE + (long)tid * SC_PER;
    int loc[SC_PER];
    int s = 0;
    #pragma unroll
    for (int j = 0; j < SC_PER; ++j) {
        long idx = base + j;
        int v = (idx < n) ? in[idx] : 0;
        loc[j] = s; s += v;
    }
    sh[tid] = s;
    __syncthreads();
    for (int o = 1; o < SC_BLK; o <<= 1) {
        int t = (tid >= o) ? sh[tid - o] : 0;
        __syncthreads();
        sh[tid] += t;
        __syncthreads();
    }
    int excl = sh[tid] - s;
    #pragma unroll
    for (int j = 0; j < SC_PER; ++j) {
        long idx = base + j;
        if (idx < n) out[idx] = excl + loc[j];
    }
    if (tid == SC_BLK - 1) partials[b] = sh[tid];
}

__global__ __launch_bounds__(1024) void scan_partials_kernel(
    int* __restrict__ partials, int np, int* __restrict__ out_total)
{
    __shared__ int sh[1024];
    int tid = threadIdx.x;
    int v = (tid < np) ? partials[tid] : 0;
    sh[tid] = v;
    __syncthreads();
    for (int o = 1; o < 1024; o <<= 1) {
        int t = (tid >= o) ? sh[tid - o] : 0;
        __syncthreads();
        sh[tid] += t;
        __syncthreads();
    }
    if (tid < np) partials[tid] = sh[tid] - v;   // exclusive
    if (tid == 1023) out_total[0] = sh[1023];    // total -> out[n]
}

__global__ __launch_bounds__(SC_BLK) void scan_add_kernel(
    int* __restrict__ out, int n, const int* __restrict__ partials)
{
    int b = blockIdx.x;
    int add = partials[b];
    long base = (long)b * SC_TILE + threadIdx.x;
    #pragma unroll
    for (int j = 0; j < SC_PER; ++j) {
        long idx = base + (long)j * SC_BLK;
        if (idx < n) out[idx] += add;
    }
}

static inline void run_exscan(const int* in, int* out, int n, int* partials, hipStream_t s) {
    int nb = (n + SC_TILE - 1) / SC_TILE;
    scan_blocks_kernel<<<nb, SC_BLK, 0, s>>>(in, n, out, partials);
    scan_partials_kernel<<<1, 1024, 0, s>>>(partials, nb, out + n);
    scan_add_kernel<<<nb, SC_BLK, 0, s>>>(out, n, partials);
}

__global__ void scatter_kernel(const int* __restrict__ rows, int* __restrict__ cur,
                               int* __restrict__ list, int n) {
    int i = blockIdx.x * blockDim.x + threadIdx.x;
    if (i < n) {
        int r = rows[i];
        int pos = atomicAdd(&cur[r], 1);
        list[pos] = i;
    }
}

__global__ void dinv_kernel(const int* __restrict__ cnt, float* __restrict__ dinv, int n) {
    int i = blockIdx.x * blockDim.x + threadIdx.x;
    if (i < n) {
        int c = cnt[i];
        dinv[i] = (c > 0) ? 1.0f / sqrtf((float)c) : 0.0f;
    }
}

// compact slot assignment for qualifier-bearing edges
__global__ void assign_kernel(const int* __restrict__ qcnt, int* __restrict__ qidx,
                              int* __restrict__ elist, int* __restrict__ nq) {
    int e = blockIdx.x * blockDim.x + threadIdx.x;
    if (e < NE) {
        if (qcnt[e] > 0) {
            int s = atomicAdd(nq, 1);
            qidx[e] = s;
            elist[s] = e;
        } else {
            qidx[e] = -1;
        }
    }
}

// ---------------------------------------------------------------------------
// Rotation kernels — 256-thread blocks, one item per 64-lane wave (4/block)
// ---------------------------------------------------------------------------
// qsum_c[slot] = sum over qualifiers of edge elist[slot] of rotate(x[qe], rel_all[qr])
__global__ __launch_bounds__(256) void qual_agg_kernel(
    const float* __restrict__ x, const float* __restrict__ rel_all,
    const int* __restrict__ qptr, const int* __restrict__ qlist,
    const int* __restrict__ qrel, const int* __restrict__ qent,
    const int* __restrict__ elist, const int* __restrict__ nq,
    float* __restrict__ qsum_c)
{
    int slot = blockIdx.x * 4 + (threadIdx.x >> 6);
    if (slot >= nq[0]) return;
    int e = elist[slot];
    int lane = threadIdx.x & 63;
    int p0 = lane;
    int p1 = lane + 64;
    bool has1 = (p1 < DH);
    float ar0 = 0.f, ai0 = 0.f, ar1 = 0.f, ai1 = 0.f;
    int s = qptr[e], t = qptr[e + 1];
    for (int i = s; i < t; ++i) {
        int q = qlist[i];
        int ent = qent[q];
        int rel = qrel[q];
        const float* xr = x + (long)ent * DIM;
        const float* rp = rel_all + (long)rel * DIM;
        {
            float hr = xr[p0], hi = xr[p0 + DH];
            float rr = rp[p0], ri = rp[p0 + DH];
            ar0 += hr * rr - hi * ri;
            ai0 += hr * ri + hi * rr;
        }
        if (has1) {
            float hr = xr[p1], hi = xr[p1 + DH];
            float rr = rp[p1], ri = rp[p1 + DH];
            ar1 += hr * rr - hi * ri;
            ai1 += hr * ri + hi * rr;
        }
    }
    float* o = qsum_c + (long)slot * DIM;
    o[p0] = ar0; o[p0 + DH] = ai0;
    if (has1) { o[p1] = ar1; o[p1 + DH] = ai1; }
}

// out[row, col_off..col_off+200) = sum over CSR edges of
//   rotate(x[col], alpha*rel_all[etype+off] + q_edge_c[qidx[e]]) * norm
__global__ __launch_bounds__(256) void edge_agg_kernel(
    const float* __restrict__ x, const float* __restrict__ rel_all,
    const float* __restrict__ q_edge_c, const int* __restrict__ qidx,
    const int* __restrict__ ptr, const int* __restrict__ list,
    const int* __restrict__ other, const int* __restrict__ etype,
    const float* __restrict__ dinv, int rel_off,
    float* __restrict__ out, int ldo, int col_off)
{
    int n = blockIdx.x * 4 + (threadIdx.x >> 6);
    if (n >= NN) return;
    int lane = threadIdx.x & 63;
    int p0 = lane;
    int p1 = lane + 64;
    bool has1 = (p1 < DH);
    float ar0 = 0.f, ai0 = 0.f, ar1 = 0.f, ai1 = 0.f;
    int s = ptr[n], e = ptr[n + 1];
    float dn = dinv[n];
    for (int i = s; i < e; ++i) {
        int eid = list[i];
        int col = other[eid];
        int t = etype[eid] + rel_off;
        int qi = qidx[eid];
        float norm = dn * dinv[col];
        const float* xr = x + (long)col * DIM;
        const float* rp = rel_all + (long)t * DIM;
        {
            float hr = xr[p0], hi = xr[p0 + DH];
            float wr = ALPHA_C * rp[p0];
            float wi = ALPHA_C * rp[p0 + DH];
            if (qi >= 0) {
                const float* qp = q_edge_c + (long)qi * DIM;
                wr += qp[p0]; wi += qp[p0 + DH];
            }
            ar0 += (hr * wr - hi * wi) * norm;
            ai0 += (hr * wi + hi * wr) * norm;
        }
        if (has1) {
            float hr = xr[p1], hi = xr[p1 + DH];
            float wr = ALPHA_C * rp[p1];
            float wi = ALPHA_C * rp[p1 + DH];
            if (qi >= 0) {
                const float* qp = q_edge_c + (long)qi * DIM;
                wr += qp[p1]; wi += qp[p1 + DH];
            }
            ar1 += (hr * wr - hi * wi) * norm;
            ai1 += (hr * wi + hi * wr) * norm;
        }
    }
    float* o = out + (long)n * ldo + col_off;
    o[p0] = ar0; o[p0 + DH] = ai0;
    if (has1) { o[p1] = ar1; o[p1 + DH] = ai1; }
}

// out[n, col_off..+200) = rotate(x[n], rel_all[last])
__global__ __launch_bounds__(256) void rot_loop_kernel(
    const float* __restrict__ x, const float* __restrict__ rel_all,
    float* __restrict__ out, int ldo, int col_off)
{
    int n = blockIdx.x * 4 + (threadIdx.x >> 6);
    if (n >= NN) return;
    int lane = threadIdx.x & 63;
    const float* rp = rel_all + (long)(RELALL - 1) * DIM;
    const float* xr = x + (long)n * DIM;
    float* o = out + (long)n * ldo + col_off;
    {
        float hr = xr[lane], hi = xr[lane + DH];
        float rr = rp[lane], ri = rp[lane + DH];
        o[lane] = hr * rr - hi * ri;
        o[lane + DH] = hr * ri + hi * rr;
    }
    int p1 = lane + 64;
    if (p1 < DH) {
        float hr = xr[p1], hi = xr[p1 + DH];
        float rr = rp[p1], ri = rp[p1 + DH];
        o[p1] = hr * rr - hi * ri;
        o[p1 + DH] = hr * ri + hi * rr;
    }
}

// zero-fill kernel (used for clean-fail path)
__global__ void zero_kernel(float* __restrict__ p, long n) {
    long i = (long)blockIdx.x * blockDim.x + threadIdx.x;
    if (i < n) p[i] = 0.f;
}

// ---------------------------------------------------------------------------
// GEMM: C(M,N) = scale*(A(M,K) @ B) [+bias] [relu] [+=C]
// B is (K,N) row-major, or (N,K) row-major if TRANSB.
// 128x128 tile, 256 threads, 8x8 microtile split 4+4 at offset 64 (2-way-max
// LDS bank conflicts, validated round 10: 1.47e6 vs 1.32e7). SINGLE-buffer
// LDS (16.9 KB) + register prefetch of the next K-tile issued before compute.
// NOTE round-11 lesson: __launch_bounds__(256,4) forced VGPR=64 -> accumulator
// spilled to scratch (10 GB/dispatch traffic, 6x slower). Plain (256) lets the
// allocator land ~112-128 VGPR naturally (round-8 variant measured 96).
// If Mdev != nullptr, effective M is read from device (<= M).
// ---------------------------------------------------------------------------
#define BM 128
#define BN 128
#define BK 16

template <bool TRANSB>
__global__ __launch_bounds__(256) void gemm_kernel(
    const float* __restrict__ A, const float* __restrict__ B, float* __restrict__ C,
    int M, int K, int Ncols, int ldc,
    float scale, const float* __restrict__ bias, int relu, int acc,
    const int* __restrict__ Mdev)
{
    int Meff = Mdev ? Mdev[0] : M;
    int row0 = blockIdx.y * BM;
    if (row0 >= Meff) return;
    int col0 = blockIdx.x * BN;
    __shared__ float As[BK][BM + 4];
    __shared__ float Bs[BK][BN + 4];
    int tid = threadIdx.x;
    int tm = tid >> 4;      // 0..15 -> rows {tm*4+i, 64+tm*4+i}
    int tn = tid & 15;      // 0..15 -> cols {tn*4+j, 64+tn*4+j}
    float accv[8][8] = {{0.f}};
    int ktiles = (K + BK - 1) / BK;

    float4 ra[2], rb[2];

    // --- staging loads: global -> regs (tile kt) ---
    auto loadA = [&](int kt) {
        int k0 = kt * BK;
        #pragma unroll
        for (int i = 0; i < 2; ++i) {
            int f4 = tid + i * 256;           // 0..511
            int m  = f4 >> 2;                 // 0..127
            int kq = (f4 & 3) * 4;            // 0,4,8,12
            int gm = row0 + m, gk = k0 + kq;
            float4 v = make_float4(0.f, 0.f, 0.f, 0.f);
            if (gm < Meff) {
                if (gk + 3 < K) {
                    v = *reinterpret_cast<const float4*>(A + (long)gm * K + gk);
                } else {
                    float t0[4] = {0.f, 0.f, 0.f, 0.f};
                    #pragma unroll
                    for (int j = 0; j < 4; ++j) if (gk + j < K) t0[j] = A[(long)gm * K + gk + j];
                    v = make_float4(t0[0], t0[1], t0[2], t0[3]);
                }
            }
            ra[i] = v;
        }
    };
    auto loadB = [&](int kt) {
        int k0 = kt * BK;
        if (!TRANSB) {
            #pragma unroll
            for (int i = 0; i < 2; ++i) {
                int f4 = tid + i * 256;       // 0..511
                int k  = f4 >> 5;             // 0..15
                int n4 = (f4 & 31) * 4;       // 0..124
                int gk = k0 + k, gn = col0 + n4;
                float4 v = make_float4(0.f, 0.f, 0.f, 0.f);
                if (gk < K) {
                    if (gn + 3 < Ncols) {
                        v = *reinterpret_cast<const float4*>(B + (long)gk * Ncols + gn);
                    } else {
                        float t0[4] = {0.f, 0.f, 0.f, 0.f};
                        #pragma unroll
                        for (int j = 0; j < 4; ++j) if (gn + j < Ncols) t0[j] = B[(long)gk * Ncols + gn + j];
                        v = make_float4(t0[0], t0[1], t0[2], t0[3]);
                    }
                }
                rb[i] = v;
            }
        } else {
            #pragma unroll
            for (int i = 0; i < 2; ++i) {
                int f4 = tid + i * 256;       // 0..511
                int n  = f4 >> 2;             // 0..127
                int kq = (f4 & 3) * 4;        // 0,4,8,12
                int gn = col0 + n, gk = k0 + kq;
                float4 v = make_float4(0.f, 0.f, 0.f, 0.f);
                if (gn < Ncols) {
                    if (gk + 3 < K) {
                        v = *reinterpret_cast<const float4*>(B + (long)gn * K + gk);
                    } else {
                        float t0[4] = {0.f, 0.f, 0.f, 0.f};
                        #pragma unroll
                        for (int j = 0; j < 4; ++j) if (gk + j < K) t0[j] = B[(long)gn * K + gk + j];
                        v = make_float4(t0[0], t0[1], t0[2], t0[3]);
                    }
                }
                rb[i] = v;
            }
        }
    };
    auto storeA = [&]() {
        #pragma unroll
        for (int i = 0; i < 2; ++i) {
            int f4 = tid + i * 256;
            int m  = f4 >> 2;
            int kq = (f4 & 3) * 4;
            As[kq + 0][m] = ra[i].x; As[kq + 1][m] = ra[i].y;
            As[kq + 2][m] = ra[i].z; As[kq + 3][m] = ra[i].w;
        }
    };
    auto storeB = [&]() {
        if (!TRANSB) {
            #pragma unroll
            for (int i = 0; i < 2; ++i) {
                int f4 = tid + i * 256;
                int k  = f4 >> 5;
                int n4 = (f4 & 31) * 4;
                Bs[k][n4 + 0] = rb[i].x; Bs[k][n4 + 1] = rb[i].y;
                Bs[k][n4 + 2] = rb[i].z; Bs[k][n4 + 3] = rb[i].w;
            }
        } else {
            #pragma unroll
            for (int i = 0; i < 2; ++i) {
                int f4 = tid + i * 256;
                int n  = f4 >> 2;
                int kq = (f4 & 3) * 4;
                Bs[kq + 0][n] = rb[i].x; Bs[kq + 1][n] = rb[i].y;
                Bs[kq + 2][n] = rb[i].z; Bs[kq + 3][n] = rb[i].w;
            }
        }
    };

    // prologue: tile 0 -> LDS
    loadA(0); loadB(0);
    storeA(); storeB();

    for (int kt = 0; kt < ktiles; ++kt) {
        __syncthreads();                           // tile kt's LDS writes visible
        bool more = (kt + 1 < ktiles);
        if (more) { loadA(kt + 1); loadB(kt + 1); }  // issue next-tile global loads
        #pragma unroll
        for (int k = 0; k < BK; ++k) {             // 1024 FMAs hide the load latency
            float a[8], b[8];
            *reinterpret_cast<float4*>(&a[0]) = *reinterpret_cast<const float4*>(&As[k][tm * 4]);
            *reinterpret_cast<float4*>(&a[4]) = *reinterpret_cast<const float4*>(&As[k][64 + tm * 4]);
            *reinterpret_cast<float4*>(&b[0]) = *reinterpret_cast<const float4*>(&Bs[k][tn * 4]);
            *reinterpret_cast<float4*>(&b[4]) = *reinterpret_cast<const float4*>(&Bs[k][64 + tn * 4]);
            #pragma unroll
            for (int i = 0; i < 8; ++i)
                #pragma unroll
                for (int j = 0; j < 8; ++j)
                    accv[i][j] += a[i] * b[j];
        }
        __syncthreads();                           // all reads of tile kt done
        if (more) { storeA(); storeB(); }          // overwrite LDS with tile kt+1
    }

    #pragma unroll
    for (int i = 0; i < 8; ++i) {
        int gm = row0 + ((i < 4) ? (tm * 4 + i) : (64 + tm * 4 + (i - 4)));
        if (gm >= Meff) continue;
        #pragma unroll
        for (int j = 0; j < 8; ++j) {
            int gn = col0 + ((j < 4) ? (tn * 4 + j) : (64 + tn * 4 + (j - 4)));
            if (gn >= Ncols) continue;
            float v = accv[i][j] * scale;
            if (bias) v += bias[gn];
            if (relu) v = fmaxf(v, 0.f);
            long off = (long)gm * ldc + gn;
            if (acc) v += C[off];
            C[off] = v;
        }
    }
}

// ---------------------------------------------------------------------------
// BatchNorm pieces (column-wise over NN rows)
// ---------------------------------------------------------------------------
__global__ __launch_bounds__(256) void bn_stats_kernel(
    const float* __restrict__ in, float scale, int relu_in,
    float* __restrict__ s1, float* __restrict__ s2)
{
    int d = threadIdx.x;
    if (d >= DIM) return;
    float a = 0.f, b = 0.f;
    for (int r = blockIdx.x; r < NN; r += gridDim.x) {
        float v = in[(long)r * DIM + d] * scale;
        if (relu_in) v = fmaxf(v, 0.f);
        a += v;
        b += v * v;
    }
    atomicAdd(&s1[d], a);
    atomicAdd(&s2[d], b);
}

__global__ void bn_finalize_kernel(
    const float* __restrict__ s1, const float* __restrict__ s2,
    const float* __restrict__ g, const float* __restrict__ be,
    float* __restrict__ aa, float* __restrict__ cc)
{
    int d = threadIdx.x;
    if (d >= DIM) return;
    float mu = s1[d] / (float)NN;
    float var = s2[d] / (float)NN - mu * mu;
    float inv = 1.0f / sqrtf(var + BN_EPS_C);
    float a = g[d] * inv;
    aa[d] = a;
    cc[d] = be[d] - mu * a;
}

__global__ __launch_bounds__(256) void bn_apply_kernel(
    const float* __restrict__ in, float scale, int relu_in,
    const float* __restrict__ aa, const float* __restrict__ cc, int relu_out,
    float* __restrict__ out, int ldo, int col0)
{
    int d = threadIdx.x;
    if (d >= DIM) return;
    int r = blockIdx.x;
    float v = in[(long)r * DIM + d] * scale;
    if (relu_in) v = fmaxf(v, 0.f);
    v = aa[d] * v + cc[d];
    if (relu_out) v = fmaxf(v, 0.f);
    out[(long)r * ldo + col0 + d] = v;
}

// ---------------------------------------------------------------------------
// LRGA pieces
// ---------------------------------------------------------------------------
__global__ __launch_bounds__(128) void colsum_uv_kernel(
    const float* __restrict__ t, float* __restrict__ cs)
{
    int d = threadIdx.x;
    if (d >= 100) return;
    float s = 0.f;
    for (int r = blockIdx.x; r < NN; r += gridDim.x) s += t[(long)r * DIM + d];
    atomicAdd(&cs[d], s);
}

__global__ void nf_kernel(const float* __restrict__ cs, float* __restrict__ nf) {
    int lane = threadIdx.x;
    float v = (lane < 50) ? cs[lane] * cs[50 + lane] : 0.f;
    for (int off = 32; off > 0; off >>= 1) v += __shfl_down(v, off);
    if (lane == 0) nf[0] = v / (float)NN + 1e-6f;
}

__global__ __launch_bounds__(256) void vtz_kernel(
    const float* __restrict__ t, float* __restrict__ M50)
{
    __shared__ float vz[100];
    int tid = threadIdx.x;
    float acc[10];
    #pragma unroll
    for (int a = 0; a < 10; ++a) acc[a] = 0.f;
    for (int r = blockIdx.x; r < NN; r += gridDim.x) {
        if (tid < 100) vz[tid] = t[(long)r * DIM + 50 + tid];
        __syncthreads();
        #pragma unroll
        for (int a = 0; a < 10; ++a) {
            int p = tid + a * 256;
            if (p < 2500) {
                int i = p / 50, j = p % 50;
                acc[a] += vz[i] * vz[50 + j];
            }
        }
        __syncthreads();
    }
    #pragma unroll
    for (int a = 0; a < 10; ++a) {
        int p = tid + a * 256;
        if (p < 2500) atomicAdd(&M50[p], acc[a]);
    }
}

__global__ __launch_bounds__(256) void um_kernel(
    const float* __restrict__ t, const float* __restrict__ M50,
    const float* __restrict__ nf, float* __restrict__ cat)
{
    __shared__ float Ms[2500];
    int tid = threadIdx.x;
    for (int i = tid; i < 2500; i += 256) Ms[i] = M50[i];
    __syncthreads();
    int n = blockIdx.x * 256 + tid;
    if (n >= NN) return;
    float inv = 1.0f / nf[0];
    float acc[50];
    #pragma unroll
    for (int j = 0; j < 50; ++j) acc[j] = 0.f;
    for (int k = 0; k < 50; ++k) {
        float u = t[(long)n * DIM + k];
        #pragma unroll
        for (int j = 0; j < 50; ++j) acc[j] += u * Ms[k * 50 + j];
    }
    #pragma unroll
    for (int j = 0; j < 50; ++j) cat[(long)n * 500 + j] = acc[j] * inv;
}

__global__ __launch_bounds__(256) void copy_cols_kernel(
    const float* __restrict__ src, int lds_, int sc0,
    float* __restrict__ dst, int ldd, int dc0,
    int rows, int cols)
{
    int i = blockIdx.x * blockDim.x + threadIdx.x;
    int total = rows * cols;
    if (i >= total) return;
    int r = i / cols, c = i % cols;
    dst[(long)r * ldd + dc0 + c] = src[(long)r * lds_ + sc0 + c];
}

// ---------------------------------------------------------------------------
static inline void launch_gemm(bool transB, const float* A, const float* B, float* C,
                               int Mmax, int K, int Ncols, int ldc, float scale,
                               const float* bias, int relu, int acc,
                               const int* Mdev, hipStream_t s)
{
    dim3 grid((Ncols + BN - 1) / BN, (Mmax + BM - 1) / BM);
    if (transB)
        gemm_kernel<true><<<grid, 256, 0, s>>>(A, B, C, Mmax, K, Ncols, ldc, scale, bias, relu, acc, Mdev);
    else
        gemm_kernel<false><<<grid, 256, 0, s>>>(A, B, C, Mmax, K, Ncols, ldc, scale, bias, relu, acc, Mdev);
}

extern "C" void kernel_launch(void* const* d_in, const int* in_sizes, int n_in,
                              void* d_out, int out_size, void* d_ws, size_t ws_size,
                              hipStream_t stream)
{
    // inputs
    const int*   edge_index = (const int*)d_in[0];        // (2, NE)
    const int*   ei0        = edge_index;
    const int*   ei1        = edge_index + NE;
    const int*   edge_type  = (const int*)d_in[1];        // (NE,)
    const int*   quals_rel  = (const int*)d_in[2];        // (NQ,)
    const int*   quals_ent  = (const int*)d_in[3];
    const int*   quals_edge = (const int*)d_in[4];
    const float* ent_emb    = (const float*)d_in[5];      // (NN, DIM)
    const float* init_rel   = (const float*)d_in[6];      // (801, DIM)
    const float* loop_rel   = (const float*)d_in[7];      // (2, DIM)
    const float* w_in       = (const float*)d_in[8];      // (2, DIM, DIM)
    const float* w_out      = (const float*)d_in[9];
    const float* w_loop     = (const float*)d_in[10];
    const float* w_rel      = (const float*)d_in[11];
    const float* w_q        = (const float*)d_in[12];
    const float* conv_gamma = (const float*)d_in[13];     // (2, DIM)
    const float* conv_beta  = (const float*)d_in[14];
    const float* lrga_w     = (const float*)d_in[15];     // (2, 200, DIM)
    const float* lrga_b     = (const float*)d_in[16];     // (2, 200)
    const float* dimred_w   = (const float*)d_in[17];     // (2, DIM, 500)
    const float* dimred_b   = (const float*)d_in[18];     // (2, DIM)
    const float* fuse_gamma = (const float*)d_in[19];     // (DIM,)
    const float* fuse_beta  = (const float*)d_in[20];

    float* out_x = (float*)d_out;                          // NN*DIM
    float* out_r = (float*)d_out + (long)NN * DIM;         // 801*DIM

    // ---- workspace carve with lifetime-based aliasing (~249 MB total) ----
    char* wp = (char*)d_ws;
    auto alloc = [&](size_t bytes) -> void* {
        void* p = (void*)wp;
        wp += (bytes + 255) & ~(size_t)255;
        return p;
    };
    // Region A (30e6 floats = 120 MB): qsum_c, then pre3|conv_sum|tbuf
    float* regionA  = (float*)alloc(sizeof(float) * (size_t)NQ * DIM);
    float* qsum_c   = regionA;                       // live: qual_agg -> q_edge GEMM
    float* pre3     = regionA;                       // NN*600, live: edge_agg -> conv GEMM
    float* conv_sum = regionA + (size_t)NN * 600;    // NN*200, live: conv GEMM -> bn_apply
    float* tbuf     = conv_sum + (size_t)NN * DIM;   // NN*200, live: LRGA GEMM -> copy T
    // Region B (30e6 floats = 120 MB): q_edge_c, then cat|hbuf
    float* regionB  = (float*)alloc(sizeof(float) * (size_t)NQ * DIM);
    float* q_edge_c = regionB;                       // live: q GEMM -> edge_agg
    float* cat      = regionB;                       // NN*500, live: bn_apply -> dimred
    float* hbuf     = cat + (size_t)NN * 500;        // NN*200, live: dimred -> fuse BN (L0)
    // x_cur aliases out_x: written end of L0, last read before dimred-L1 overwrites d_out
    float* x_cur    = out_x;
    float* rel_all  = (float*)alloc(sizeof(float) * (size_t)RELALL * DIM);
    float* r_buf    = (float*)alloc(sizeof(float) * (size_t)RELROWS * DIM);
    float* wcat     = (float*)alloc(sizeof(float) * 600 * DIM);
    float* dinv0    = (float*)alloc(sizeof(float) * NN);
    float* dinv1    = (float*)alloc(sizeof(float) * NN);
    float* s1       = (float*)alloc(sizeof(float) * DIM);
    float* s2       = (float*)alloc(sizeof(float) * DIM);
    float* aa       = (float*)alloc(sizeof(float) * DIM);
    float* cc       = (float*)alloc(sizeof(float) * DIM);
    float* csUV     = (float*)alloc(sizeof(float) * 100);
    float* nfv      = (float*)alloc(sizeof(float) * 1);
    float* M50      = (float*)alloc(sizeof(float) * 2500);
    int* cnt0  = (int*)alloc(sizeof(int) * NN);
    int* ptr0  = (int*)alloc(sizeof(int) * (NN + 1));
    int* cur0  = (int*)alloc(sizeof(int) * NN);
    int* list0 = (int*)alloc(sizeof(int) * NE);
    int* cnt1  = (int*)alloc(sizeof(int) * NN);
    int* ptr1  = (int*)alloc(sizeof(int) * (NN + 1));
    int* cur1  = (int*)alloc(sizeof(int) * NN);
    int* list1 = (int*)alloc(sizeof(int) * NE);
    int* qcnt  = (int*)alloc(sizeof(int) * NE);
    int* qptr  = (int*)alloc(sizeof(int) * (NE + 1));
    int* qcur  = (int*)alloc(sizeof(int) * NE);
    int* qlist = (int*)alloc(sizeof(int) * NQ);
    int* qidx  = (int*)alloc(sizeof(int) * NE);
    int* elist = (int*)alloc(sizeof(int) * NQ);
    int* nq    = (int*)alloc(sizeof(int) * 1);
    int* partials = (int*)alloc(sizeof(int) * 1024);

    // ---- workspace-size guard: clean deterministic fail instead of GPU abort ----
    size_t needed = (size_t)(wp - (char*)d_ws);
    if (needed > ws_size) {
        long total_out = (long)out_size;
        zero_kernel<<<(int)((total_out + 255) / 256), 256, 0, stream>>>((float*)d_out, total_out);
        return;
    }

    // ---- CSR build (per call; inputs restored before every timed launch) ----
    hipMemsetAsync(cnt0, 0, sizeof(int) * NN, stream);
    hipMemsetAsync(cnt1, 0, sizeof(int) * NN, stream);
    hipMemsetAsync(qcnt, 0, sizeof(int) * NE, stream);
    hipMemsetAsync(nq, 0, sizeof(int), stream);
    hist_kernel<<<(NE + 255) / 256, 256, 0, stream>>>(ei0, NE, cnt0);
    hist_kernel<<<(NE + 255) / 256, 256, 0, stream>>>(ei1, NE, cnt1);
    hist_kernel<<<(NQ + 255) / 256, 256, 0, stream>>>(quals_edge, NQ, qcnt);
    run_exscan(cnt0, ptr0, NN, partials, stream);
    run_exscan(cnt1, ptr1, NN, partials, stream);
    run_exscan(qcnt, qptr, NE, partials, stream);
    hipMemcpyAsync(cur0, ptr0, sizeof(int) * NN, hipMemcpyDeviceToDevice, stream);
    hipMemcpyAsync(cur1, ptr1, sizeof(int) * NN, hipMemcpyDeviceToDevice, stream);
    hipMemcpyAsync(qcur, qptr, sizeof(int) * NE, hipMemcpyDeviceToDevice, stream);
    scatter_kernel<<<(NE + 255) / 256, 256, 0, stream>>>(ei0, cur0, list0, NE);
    scatter_kernel<<<(NE + 255) / 256, 256, 0, stream>>>(ei1, cur1, list1, NE);
    scatter_kernel<<<(NQ + 255) / 256, 256, 0, stream>>>(quals_edge, qcur, qlist, NQ);
    dinv_kernel<<<(NN + 255) / 256, 256, 0, stream>>>(cnt0, dinv0, NN);
    dinv_kernel<<<(NN + 255) / 256, 256, 0, stream>>>(cnt1, dinv1, NN);
    assign_kernel<<<(NE + 255) / 256, 256, 0, stream>>>(qcnt, qidx, elist, nq);

    // ---- layer loop (L=2) ----
    for (int i = 0; i < 2; ++i) {
        const float* xin  = (i == 0) ? ent_emb : x_cur;
        const float* rsrc = (i == 0) ? init_rel : r_buf;

        // rel_all = [r ; loop_rel[i]]
        hipMemcpyAsync(rel_all, rsrc, sizeof(float) * RELROWS * DIM,
                       hipMemcpyDeviceToDevice, stream);
        hipMemcpyAsync(rel_all + (long)RELROWS * DIM, loop_rel + (long)i * DIM,
                       sizeof(float) * DIM, hipMemcpyDeviceToDevice, stream);

        // qualifier aggregation into compact rows (shared by both directions)
        qual_agg_kernel<<<(NQ + 3) / 4, 256, 0, stream>>>(xin, rel_all, qptr, qlist,
                                               quals_rel, quals_ent, elist, nq, qsum_c);
        // q_edge_c = (1-alpha) * qsum_c @ w_q[i]   (dynamic M = *nq)
        launch_gemm(false, qsum_c, w_q + (long)i * DIM * DIM, q_edge_c,
                    NQ, DIM, DIM, DIM, 1.0f - ALPHA_C, nullptr, 0, 0, nq, stream);

        // per-direction aggregation into pre3 columns [0:200 | 200:400 | 400:600]
        // (pre3 overwrites qsum_c region - qsum dead after the GEMM above)
        edge_agg_kernel<<<(NN + 3) / 4, 256, 0, stream>>>(xin, rel_all, q_edge_c, qidx,
                                               ptr0, list0, ei1, edge_type, dinv0, 0,
                                               pre3, 600, 0);
        edge_agg_kernel<<<(NN + 3) / 4, 256, 0, stream>>>(xin, rel_all, q_edge_c, qidx,
                                               ptr1, list1, ei0, edge_type, dinv1, RRR,
                                               pre3, 600, 200);
        rot_loop_kernel<<<(NN + 3) / 4, 256, 0, stream>>>(xin, rel_all, pre3, 600, 400);

        // stacked conv weights: wcat = [w_in; w_out; w_loop] (600 x 200)
        hipMemcpyAsync(wcat,                 w_in   + (long)i * DIM * DIM, sizeof(float) * DIM * DIM, hipMemcpyDeviceToDevice, stream);
        hipMemcpyAsync(wcat + DIM * DIM,     w_out  + (long)i * DIM * DIM, sizeof(float) * DIM * DIM, hipMemcpyDeviceToDevice, stream);
        hipMemcpyAsync(wcat + 2 * DIM * DIM, w_loop + (long)i * DIM * DIM, sizeof(float) * DIM * DIM, hipMemcpyDeviceToDevice, stream);
        // conv_sum = pre3 @ wcat  (single K=600 GEMM)
        launch_gemm(false, pre3, wcat, conv_sum, NN, 600, DIM, DIM, 1.f, nullptr, 0, 0, nullptr, stream);

        // conv BN on conv_sum/3, relu -> x_local into cat[:,100:300]
        // (cat overwrites q_edge_c region - q_edge dead after edge_agg)
        hipMemsetAsync(s1, 0, sizeof(float) * DIM, stream);
        hipMemsetAsync(s2, 0, sizeof(float) * DIM, stream);
        bn_stats_kernel<<<512, 256, 0, stream>>>(conv_sum, 1.0f / 3.0f, 0, s1, s2);
        bn_finalize_kernel<<<1, 256, 0, stream>>>(s1, s2, conv_gamma + (long)i * DIM,
                                                  conv_beta + (long)i * DIM, aa, cc);
        bn_apply_kernel<<<NN, 256, 0, stream>>>(conv_sum, 1.0f / 3.0f, 0, aa, cc, 1,
                                                cat, 500, 100);

        // LRGA on xin: t = relu(x @ lrga_w.T + lrga_b)  (tbuf in regionA tail - safe)
        launch_gemm(true, xin, lrga_w + (long)i * 200 * DIM, tbuf,
                    NN, DIM, 200, 200, 1.f, lrga_b + (long)i * 200, 1, 0, nullptr, stream);
        hipMemsetAsync(csUV, 0, sizeof(float) * 100, stream);
        hipMemsetAsync(M50, 0, sizeof(float) * 2500, stream);
        colsum_uv_kernel<<<256, 128, 0, stream>>>(tbuf, csUV);
        nf_kernel<<<1, 64, 0, stream>>>(csUV, nfv);
        vtz_kernel<<<128, 256, 0, stream>>>(tbuf, M50);
        um_kernel<<<(NN + 255) / 256, 256, 0, stream>>>(tbuf, M50, nfv, cat);
        // cat[:,50:100] = T = t[:,150:200]
        copy_cols_kernel<<<(NN * 50 + 255) / 256, 256, 0, stream>>>(
            tbuf, DIM, 150, cat, 500, 50, NN, 50);
        // cat[:,300:500] = x
        copy_cols_kernel<<<(NN * DIM + 255) / 256, 256, 0, stream>>>(
            xin, DIM, 0, cat, 500, 300, NN, DIM);

        // dimred: h = cat @ dimred_w[i].T + dimred_b[i]
        float* hdst = (i == 0) ? hbuf : out_x;
        launch_gemm(true, cat, dimred_w + (long)i * DIM * 500, hdst,
                    NN, 500, DIM, DIM, 1.f, dimred_b + (long)i * DIM, 0, 0, nullptr, stream);

        if (i == 0) {
            // x = BN(relu(h), fuse_gamma, fuse_beta)  -> x_cur (= out_x scratch)
            hipMemsetAsync(s1, 0, sizeof(float) * DIM, stream);
            hipMemsetAsync(s2, 0, sizeof(float) * DIM, stream);
            bn_stats_kernel<<<512, 256, 0, stream>>>(hdst, 1.0f, 1, s1, s2);
            bn_finalize_kernel<<<1, 256, 0, stream>>>(s1, s2, fuse_gamma, fuse_beta, aa, cc);
            bn_apply_kernel<<<NN, 256, 0, stream>>>(hdst, 1.0f, 1, aa, cc, 0,
                                                    x_cur, DIM, 0);
        }

        // r update: (rel_all @ w_rel[i]) keep rows 0..800
        float* rdst = (i == 0) ? r_buf : out_r;
        launch_gemm(false, rel_all, w_rel + (long)i * DIM * DIM, rdst,
                    RELROWS, DIM, DIM, DIM, 1.f, nullptr, 0, 0, nullptr, stream);
    }
}

// Round 14
// 2394.845 us; speedup vs baseline: 6.5170x; 1.3160x over previous
//
#include <hip/hip_runtime.h>
#include <cstdint>
#include <cstddef>

// Problem constants (match reference)
#define NN      30000     // nodes
#define NE      250000    // edges (one direction)
#define NQ      150000    // qualifiers
#define DIM     200
#define DH      100       // DIM/2
#define RRR     400       // R
#define RELROWS 801       // 2R+1
#define RELALL  802       // 2R+2 (with loop row)
#define ALPHA_C 0.8f
#define BN_EPS_C 1e-5f

// ---------------------------------------------------------------------------
// CSR build helpers
// ---------------------------------------------------------------------------
__global__ void hist_kernel(const int* __restrict__ idx, int n, int* __restrict__ cnt) {
    int i = blockIdx.x * blockDim.x + threadIdx.x;
    if (i < n) atomicAdd(&cnt[idx[i]], 1);
}

// ---- two-level exclusive scan (out has n+1 entries, out[n] = total) ----
#define SC_BLK 256
#define SC_PER 16
#define SC_TILE (SC_BLK * SC_PER)   // 4096

__global__ __launch_bounds__(SC_BLK) void scan_blocks_kernel(
    const int* __restrict__ in, int n, int* __restrict__ out, int* __restrict__ partials)
{
    __shared__ int sh[SC_BLK];
    int b = blockIdx.x, tid = threadIdx.x;
    long base = (long)b * SC_TILE + (long)tid * SC_PER;
    int loc[SC_PER];
    int s = 0;
    #pragma unroll
    for (int j = 0; j < SC_PER; ++j) {
        long idx = base + j;
        int v = (idx < n) ? in[idx] : 0;
        loc[j] = s; s += v;
    }
    sh[tid] = s;
    __syncthreads();
    for (int o = 1; o < SC_BLK; o <<= 1) {
        int t = (tid >= o) ? sh[tid - o] : 0;
        __syncthreads();
        sh[tid] += t;
        __syncthreads();
    }
    int excl = sh[tid] - s;
    #pragma unroll
    for (int j = 0; j < SC_PER; ++j) {
        long idx = base + j;
        if (idx < n) out[idx] = excl + loc[j];
    }
    if (tid == SC_BLK - 1) partials[b] = sh[tid];
}

__global__ __launch_bounds__(1024) void scan_partials_kernel(
    int* __restrict__ partials, int np, int* __restrict__ out_total)
{
    __shared__ int sh[1024];
    int tid = threadIdx.x;
    int v = (tid < np) ? partials[tid] : 0;
    sh[tid] = v;
    __syncthreads();
    for (int o = 1; o < 1024; o <<= 1) {
        int t = (tid >= o) ? sh[tid - o] : 0;
        __syncthreads();
        sh[tid] += t;
        __syncthreads();
    }
    if (tid < np) partials[tid] = sh[tid] - v;   // exclusive
    if (tid == 1023) out_total[0] = sh[1023];    // total -> out[n]
}

__global__ __launch_bounds__(SC_BLK) void scan_add_kernel(
    int* __restrict__ out, int n, const int* __restrict__ partials)
{
    int b = blockIdx.x;
    int add = partials[b];
    long base = (long)b * SC_TILE + threadIdx.x;
    #pragma unroll
    for (int j = 0; j < SC_PER; ++j) {
        long idx = base + (long)j * SC_BLK;
        if (idx < n) out[idx] += add;
    }
}

static inline void run_exscan(const int* in, int* out, int n, int* partials, hipStream_t s) {
    int nb = (n + SC_TILE - 1) / SC_TILE;
    scan_blocks_kernel<<<nb, SC_BLK, 0, s>>>(in, n, out, partials);
    scan_partials_kernel<<<1, 1024, 0, s>>>(partials, nb, out + n);
    scan_add_kernel<<<nb, SC_BLK, 0, s>>>(out, n, partials);
}

__global__ void scatter_kernel(const int* __restrict__ rows, int* __restrict__ cur,
                               int* __restrict__ list, int n) {
    int i = blockIdx.x * blockDim.x + threadIdx.x;
    if (i < n) {
        int r = rows[i];
        int pos = atomicAdd(&cur[r], 1);
        list[pos] = i;
    }
}

__global__ void dinv_kernel(const int* __restrict__ cnt, float* __restrict__ dinv, int n) {
    int i = blockIdx.x * blockDim.x + threadIdx.x;
    if (i < n) {
        int c = cnt[i];
        dinv[i] = (c > 0) ? 1.0f / sqrtf((float)c) : 0.0f;
    }
}

// compact slot assignment for qualifier-bearing edges
__global__ void assign_kernel(const int* __restrict__ qcnt, int* __restrict__ qidx,
                              int* __restrict__ elist, int* __restrict__ nq) {
    int e = blockIdx.x * blockDim.x + threadIdx.x;
    if (e < NE) {
        if (qcnt[e] > 0) {
            int s = atomicAdd(nq, 1);
            qidx[e] = s;
            elist[s] = e;
        } else {
            qidx[e] = -1;
        }
    }
}

// ---------------------------------------------------------------------------
// Rotation kernels — 256-thread blocks, one item per 64-lane wave (4/block)
// ---------------------------------------------------------------------------
// qsum_c[slot] = sum over qualifiers of edge elist[slot] of rotate(x[qe], rel_all[qr])
__global__ __launch_bounds__(256) void qual_agg_kernel(
    const float* __restrict__ x, const float* __restrict__ rel_all,
    const int* __restrict__ qptr, const int* __restrict__ qlist,
    const int* __restrict__ qrel, const int* __restrict__ qent,
    const int* __restrict__ elist, const int* __restrict__ nq,
    float* __restrict__ qsum_c)
{
    int slot = blockIdx.x * 4 + (threadIdx.x >> 6);
    if (slot >= nq[0]) return;
    int e = elist[slot];
    int lane = threadIdx.x & 63;
    int p0 = lane;
    int p1 = lane + 64;
    bool has1 = (p1 < DH);
    float ar0 = 0.f, ai0 = 0.f, ar1 = 0.f, ai1 = 0.f;
    int s = qptr[e], t = qptr[e + 1];
    for (int i = s; i < t; ++i) {
        int q = qlist[i];
        int ent = qent[q];
        int rel = qrel[q];
        const float* xr = x + (long)ent * DIM;
        const float* rp = rel_all + (long)rel * DIM;
        {
            float hr = xr[p0], hi = xr[p0 + DH];
            float rr = rp[p0], ri = rp[p0 + DH];
            ar0 += hr * rr - hi * ri;
            ai0 += hr * ri + hi * rr;
        }
        if (has1) {
            float hr = xr[p1], hi = xr[p1 + DH];
            float rr = rp[p1], ri = rp[p1 + DH];
            ar1 += hr * rr - hi * ri;
            ai1 += hr * ri + hi * rr;
        }
    }
    float* o = qsum_c + (long)slot * DIM;
    o[p0] = ar0; o[p0 + DH] = ai0;
    if (has1) { o[p1] = ar1; o[p1 + DH] = ai1; }
}

// out[row, col_off..col_off+200) = sum over CSR edges of
//   rotate(x[col], alpha*rel_all[etype+off] + q_edge_c[qidx[e]]) * norm
__global__ __launch_bounds__(256) void edge_agg_kernel(
    const float* __restrict__ x, const float* __restrict__ rel_all,
    const float* __restrict__ q_edge_c, const int* __restrict__ qidx,
    const int* __restrict__ ptr, const int* __restrict__ list,
    const int* __restrict__ other, const int* __restrict__ etype,
    const float* __restrict__ dinv, int rel_off,
    float* __restrict__ out, int ldo, int col_off)
{
    int n = blockIdx.x * 4 + (threadIdx.x >> 6);
    if (n >= NN) return;
    int lane = threadIdx.x & 63;
    int p0 = lane;
    int p1 = lane + 64;
    bool has1 = (p1 < DH);
    float ar0 = 0.f, ai0 = 0.f, ar1 = 0.f, ai1 = 0.f;
    int s = ptr[n], e = ptr[n + 1];
    float dn = dinv[n];
    for (int i = s; i < e; ++i) {
        int eid = list[i];
        int col = other[eid];
        int t = etype[eid] + rel_off;
        int qi = qidx[eid];
        float norm = dn * dinv[col];
        const float* xr = x + (long)col * DIM;
        const float* rp = rel_all + (long)t * DIM;
        {
            float hr = xr[p0], hi = xr[p0 + DH];
            float wr = ALPHA_C * rp[p0];
            float wi = ALPHA_C * rp[p0 + DH];
            if (qi >= 0) {
                const float* qp = q_edge_c + (long)qi * DIM;
                wr += qp[p0]; wi += qp[p0 + DH];
            }
            ar0 += (hr * wr - hi * wi) * norm;
            ai0 += (hr * wi + hi * wr) * norm;
        }
        if (has1) {
            float hr = xr[p1], hi = xr[p1 + DH];
            float wr = ALPHA_C * rp[p1];
            float wi = ALPHA_C * rp[p1 + DH];
            if (qi >= 0) {
                const float* qp = q_edge_c + (long)qi * DIM;
                wr += qp[p1]; wi += qp[p1 + DH];
            }
            ar1 += (hr * wr - hi * wi) * norm;
            ai1 += (hr * wi + hi * wr) * norm;
        }
    }
    float* o = out + (long)n * ldo + col_off;
    o[p0] = ar0; o[p0 + DH] = ai0;
    if (has1) { o[p1] = ar1; o[p1 + DH] = ai1; }
}

// out[n, col_off..+200) = rotate(x[n], rel_all[last])
__global__ __launch_bounds__(256) void rot_loop_kernel(
    const float* __restrict__ x, const float* __restrict__ rel_all,
    float* __restrict__ out, int ldo, int col_off)
{
    int n = blockIdx.x * 4 + (threadIdx.x >> 6);
    if (n >= NN) return;
    int lane = threadIdx.x & 63;
    const float* rp = rel_all + (long)(RELALL - 1) * DIM;
    const float* xr = x + (long)n * DIM;
    float* o = out + (long)n * ldo + col_off;
    {
        float hr = xr[lane], hi = xr[lane + DH];
        float rr = rp[lane], ri = rp[lane + DH];
        o[lane] = hr * rr - hi * ri;
        o[lane + DH] = hr * ri + hi * rr;
    }
    int p1 = lane + 64;
    if (p1 < DH) {
        float hr = xr[p1], hi = xr[p1 + DH];
        float rr = rp[p1], ri = rp[p1 + DH];
        o[p1] = hr * rr - hi * ri;
        o[p1 + DH] = hr * ri + hi * rr;
    }
}

// zero-fill kernel (used for clean-fail path)
__global__ void zero_kernel(float* __restrict__ p, long n) {
    long i = (long)blockIdx.x * blockDim.x + threadIdx.x;
    if (i < n) p[i] = 0.f;
}

// ---------------------------------------------------------------------------
// GEMM: C(M,N) = scale*(A(M,K) @ B) [+bias] [relu] [+=C]
// B is (K,N) row-major, or (N,K) row-major if TRANSB.
// 128x128 tile, 256 threads, BK=16. Round-4 staging structure (direct
// global->LDS each K-tile, 2 barriers, NO persistent prefetch registers --
// measured: 96 VGPR / 19.7% occ / best GEMM time; reg-prefetch = 192 VGPR /
// 11% occ / slower; dbuf = 188 VGPR / slower; bounds(256,4) = spill disaster).
// Plus the validated conflict-split 8x8 microtile: reads at {tm*4, 64+tm*4} x
// {tn*4, 64+tn*4} -> 2-way-max LDS bank conflicts (1.47e6 vs 1.32e7).
// If Mdev != nullptr, effective M is read from device (<= M).
// ---------------------------------------------------------------------------
#define BM 128
#define BN 128
#define BK 16

template <bool TRANSB>
__global__ __launch_bounds__(256) void gemm_kernel(
    const float* __restrict__ A, const float* __restrict__ B, float* __restrict__ C,
    int M, int K, int Ncols, int ldc,
    float scale, const float* __restrict__ bias, int relu, int acc,
    const int* __restrict__ Mdev)
{
    int Meff = Mdev ? Mdev[0] : M;
    int row0 = blockIdx.y * BM;
    if (row0 >= Meff) return;
    int col0 = blockIdx.x * BN;
    __shared__ float As[BK][BM + 4];
    __shared__ float Bs[BK][BN + 4];
    int tid = threadIdx.x;
    int tm = tid >> 4;      // 0..15 -> rows {tm*4+i, 64+tm*4+i}
    int tn = tid & 15;      // 0..15 -> cols {tn*4+j, 64+tn*4+j}
    float accv[8][8] = {{0.f}};
    int ktiles = (K + BK - 1) / BK;

    for (int kt = 0; kt < ktiles; ++kt) {
        int k0 = kt * BK;
        // A tile: 128x16 = 512 float4 loads (2 per thread), direct to LDS
        #pragma unroll
        for (int i = 0; i < 2; ++i) {
            int f4 = tid + i * 256;           // 0..511
            int m  = f4 >> 2;                 // 0..127
            int kq = (f4 & 3) * 4;            // 0,4,8,12
            int gm = row0 + m, gk = k0 + kq;
            float4 v = make_float4(0.f, 0.f, 0.f, 0.f);
            if (gm < Meff) {
                if (gk + 3 < K) {
                    v = *reinterpret_cast<const float4*>(A + (long)gm * K + gk);
                } else {
                    float t0[4] = {0.f, 0.f, 0.f, 0.f};
                    #pragma unroll
                    for (int j = 0; j < 4; ++j) if (gk + j < K) t0[j] = A[(long)gm * K + gk + j];
                    v = make_float4(t0[0], t0[1], t0[2], t0[3]);
                }
            }
            As[kq + 0][m] = v.x; As[kq + 1][m] = v.y; As[kq + 2][m] = v.z; As[kq + 3][m] = v.w;
        }
        // B tile: 16x128 = 512 float4 loads (2 per thread), direct to LDS
        if (!TRANSB) {
            #pragma unroll
            for (int i = 0; i < 2; ++i) {
                int f4 = tid + i * 256;       // 0..511
                int k  = f4 >> 5;             // 0..15
                int n4 = (f4 & 31) * 4;       // 0..124
                int gk = k0 + k, gn = col0 + n4;
                float4 v = make_float4(0.f, 0.f, 0.f, 0.f);
                if (gk < K) {
                    if (gn + 3 < Ncols) {
                        v = *reinterpret_cast<const float4*>(B + (long)gk * Ncols + gn);
                    } else {
                        float t0[4] = {0.f, 0.f, 0.f, 0.f};
                        #pragma unroll
                        for (int j = 0; j < 4; ++j) if (gn + j < Ncols) t0[j] = B[(long)gk * Ncols + gn + j];
                        v = make_float4(t0[0], t0[1], t0[2], t0[3]);
                    }
                }
                Bs[k][n4 + 0] = v.x; Bs[k][n4 + 1] = v.y; Bs[k][n4 + 2] = v.z; Bs[k][n4 + 3] = v.w;
            }
        } else {
            #pragma unroll
            for (int i = 0; i < 2; ++i) {
                int f4 = tid + i * 256;       // 0..511
                int n  = f4 >> 2;             // 0..127
                int kq = (f4 & 3) * 4;        // 0,4,8,12
                int gn = col0 + n, gk = k0 + kq;
                float4 v = make_float4(0.f, 0.f, 0.f, 0.f);
                if (gn < Ncols) {
                    if (gk + 3 < K) {
                        v = *reinterpret_cast<const float4*>(B + (long)gn * K + gk);
                    } else {
                        float t0[4] = {0.f, 0.f, 0.f, 0.f};
                        #pragma unroll
                        for (int j = 0; j < 4; ++j) if (gk + j < K) t0[j] = B[(long)gn * K + gk + j];
                        v = make_float4(t0[0], t0[1], t0[2], t0[3]);
                    }
                }
                Bs[kq + 0][n] = v.x; Bs[kq + 1][n] = v.y; Bs[kq + 2][n] = v.z; Bs[kq + 3][n] = v.w;
            }
        }
        __syncthreads();
        #pragma unroll
        for (int k = 0; k < BK; ++k) {
            float a[8], b[8];
            *reinterpret_cast<float4*>(&a[0]) = *reinterpret_cast<const float4*>(&As[k][tm * 4]);
            *reinterpret_cast<float4*>(&a[4]) = *reinterpret_cast<const float4*>(&As[k][64 + tm * 4]);
            *reinterpret_cast<float4*>(&b[0]) = *reinterpret_cast<const float4*>(&Bs[k][tn * 4]);
            *reinterpret_cast<float4*>(&b[4]) = *reinterpret_cast<const float4*>(&Bs[k][64 + tn * 4]);
            #pragma unroll
            for (int i = 0; i < 8; ++i)
                #pragma unroll
                for (int j = 0; j < 8; ++j)
                    accv[i][j] += a[i] * b[j];
        }
        __syncthreads();
    }

    #pragma unroll
    for (int i = 0; i < 8; ++i) {
        int gm = row0 + ((i < 4) ? (tm * 4 + i) : (64 + tm * 4 + (i - 4)));
        if (gm >= Meff) continue;
        #pragma unroll
        for (int j = 0; j < 8; ++j) {
            int gn = col0 + ((j < 4) ? (tn * 4 + j) : (64 + tn * 4 + (j - 4)));
            if (gn >= Ncols) continue;
            float v = accv[i][j] * scale;
            if (bias) v += bias[gn];
            if (relu) v = fmaxf(v, 0.f);
            long off = (long)gm * ldc + gn;
            if (acc) v += C[off];
            C[off] = v;
        }
    }
}

// ---------------------------------------------------------------------------
// BatchNorm pieces (column-wise over NN rows)
// ---------------------------------------------------------------------------
__global__ __launch_bounds__(256) void bn_stats_kernel(
    const float* __restrict__ in, float scale, int relu_in,
    float* __restrict__ s1, float* __restrict__ s2)
{
    int d = threadIdx.x;
    if (d >= DIM) return;
    float a = 0.f, b = 0.f;
    for (int r = blockIdx.x; r < NN; r += gridDim.x) {
        float v = in[(long)r * DIM + d] * scale;
        if (relu_in) v = fmaxf(v, 0.f);
        a += v;
        b += v * v;
    }
    atomicAdd(&s1[d], a);
    atomicAdd(&s2[d], b);
}

__global__ void bn_finalize_kernel(
    const float* __restrict__ s1, const float* __restrict__ s2,
    const float* __restrict__ g, const float* __restrict__ be,
    float* __restrict__ aa, float* __restrict__ cc)
{
    int d = threadIdx.x;
    if (d >= DIM) return;
    float mu = s1[d] / (float)NN;
    float var = s2[d] / (float)NN - mu * mu;
    float inv = 1.0f / sqrtf(var + BN_EPS_C);
    float a = g[d] * inv;
    aa[d] = a;
    cc[d] = be[d] - mu * a;
}

__global__ __launch_bounds__(256) void bn_apply_kernel(
    const float* __restrict__ in, float scale, int relu_in,
    const float* __restrict__ aa, const float* __restrict__ cc, int relu_out,
    float* __restrict__ out, int ldo, int col0)
{
    int d = threadIdx.x;
    if (d >= DIM) return;
    int r = blockIdx.x;
    float v = in[(long)r * DIM + d] * scale;
    if (relu_in) v = fmaxf(v, 0.f);
    v = aa[d] * v + cc[d];
    if (relu_out) v = fmaxf(v, 0.f);
    out[(long)r * ldo + col0 + d] = v;
}

// ---------------------------------------------------------------------------
// LRGA pieces
// ---------------------------------------------------------------------------
__global__ __launch_bounds__(128) void colsum_uv_kernel(
    const float* __restrict__ t, float* __restrict__ cs)
{
    int d = threadIdx.x;
    if (d >= 100) return;
    float s = 0.f;
    for (int r = blockIdx.x; r < NN; r += gridDim.x) s += t[(long)r * DIM + d];
    atomicAdd(&cs[d], s);
}

__global__ void nf_kernel(const float* __restrict__ cs, float* __restrict__ nf) {
    int lane = threadIdx.x;
    float v = (lane < 50) ? cs[lane] * cs[50 + lane] : 0.f;
    for (int off = 32; off > 0; off >>= 1) v += __shfl_down(v, off);
    if (lane == 0) nf[0] = v / (float)NN + 1e-6f;
}

__global__ __launch_bounds__(256) void vtz_kernel(
    const float* __restrict__ t, float* __restrict__ M50)
{
    __shared__ float vz[100];
    int tid = threadIdx.x;
    float acc[10];
    #pragma unroll
    for (int a = 0; a < 10; ++a) acc[a] = 0.f;
    for (int r = blockIdx.x; r < NN; r += gridDim.x) {
        if (tid < 100) vz[tid] = t[(long)r * DIM + 50 + tid];
        __syncthreads();
        #pragma unroll
        for (int a = 0; a < 10; ++a) {
            int p = tid + a * 256;
            if (p < 2500) {
                int i = p / 50, j = p % 50;
                acc[a] += vz[i] * vz[50 + j];
            }
        }
        __syncthreads();
    }
    #pragma unroll
    for (int a = 0; a < 10; ++a) {
        int p = tid + a * 256;
        if (p < 2500) atomicAdd(&M50[p], acc[a]);
    }
}

__global__ __launch_bounds__(256) void um_kernel(
    const float* __restrict__ t, const float* __restrict__ M50,
    const float* __restrict__ nf, float* __restrict__ cat)
{
    __shared__ float Ms[2500];
    int tid = threadIdx.x;
    for (int i = tid; i < 2500; i += 256) Ms[i] = M50[i];
    __syncthreads();
    int n = blockIdx.x * 256 + tid;
    if (n >= NN) return;
    float inv = 1.0f / nf[0];
    float acc[50];
    #pragma unroll
    for (int j = 0; j < 50; ++j) acc[j] = 0.f;
    for (int k = 0; k < 50; ++k) {
        float u = t[(long)n * DIM + k];
        #pragma unroll
        for (int j = 0; j < 50; ++j) acc[j] += u * Ms[k * 50 + j];
    }
    #pragma unroll
    for (int j = 0; j < 50; ++j) cat[(long)n * 500 + j] = acc[j] * inv;
}

__global__ __launch_bounds__(256) void copy_cols_kernel(
    const float* __restrict__ src, int lds_, int sc0,
    float* __restrict__ dst, int ldd, int dc0,
    int rows, int cols)
{
    int i = blockIdx.x * blockDim.x + threadIdx.x;
    int total = rows * cols;
    if (i >= total) return;
    int r = i / cols, c = i % cols;
    dst[(long)r * ldd + dc0 + c] = src[(long)r * lds_ + sc0 + c];
}

// ---------------------------------------------------------------------------
static inline void launch_gemm(bool transB, const float* A, const float* B, float* C,
                               int Mmax, int K, int Ncols, int ldc, float scale,
                               const float* bias, int relu, int acc,
                               const int* Mdev, hipStream_t s)
{
    dim3 grid((Ncols + BN - 1) / BN, (Mmax + BM - 1) / BM);
    if (transB)
        gemm_kernel<true><<<grid, 256, 0, s>>>(A, B, C, Mmax, K, Ncols, ldc, scale, bias, relu, acc, Mdev);
    else
        gemm_kernel<false><<<grid, 256, 0, s>>>(A, B, C, Mmax, K, Ncols, ldc, scale, bias, relu, acc, Mdev);
}

extern "C" void kernel_launch(void* const* d_in, const int* in_sizes, int n_in,
                              void* d_out, int out_size, void* d_ws, size_t ws_size,
                              hipStream_t stream)
{
    // inputs
    const int*   edge_index = (const int*)d_in[0];        // (2, NE)
    const int*   ei0        = edge_index;
    const int*   ei1        = edge_index + NE;
    const int*   edge_type  = (const int*)d_in[1];        // (NE,)
    const int*   quals_rel  = (const int*)d_in[2];        // (NQ,)
    const int*   quals_ent  = (const int*)d_in[3];
    const int*   quals_edge = (const int*)d_in[4];
    const float* ent_emb    = (const float*)d_in[5];      // (NN, DIM)
    const float* init_rel   = (const float*)d_in[6];      // (801, DIM)
    const float* loop_rel   = (const float*)d_in[7];      // (2, DIM)
    const float* w_in       = (const float*)d_in[8];      // (2, DIM, DIM)
    const float* w_out      = (const float*)d_in[9];
    const float* w_loop     = (const float*)d_in[10];
    const float* w_rel      = (const float*)d_in[11];
    const float* w_q        = (const float*)d_in[12];
    const float* conv_gamma = (const float*)d_in[13];     // (2, DIM)
    const float* conv_beta  = (const float*)d_in[14];
    const float* lrga_w     = (const float*)d_in[15];     // (2, 200, DIM)
    const float* lrga_b     = (const float*)d_in[16];     // (2, 200)
    const float* dimred_w   = (const float*)d_in[17];     // (2, DIM, 500)
    const float* dimred_b   = (const float*)d_in[18];     // (2, DIM)
    const float* fuse_gamma = (const float*)d_in[19];     // (DIM,)
    const float* fuse_beta  = (const float*)d_in[20];

    float* out_x = (float*)d_out;                          // NN*DIM
    float* out_r = (float*)d_out + (long)NN * DIM;         // 801*DIM

    // ---- workspace carve with lifetime-based aliasing (~249 MB total) ----
    char* wp = (char*)d_ws;
    auto alloc = [&](size_t bytes) -> void* {
        void* p = (void*)wp;
        wp += (bytes + 255) & ~(size_t)255;
        return p;
    };
    // Region A (30e6 floats = 120 MB): qsum_c, then pre3|conv_sum|tbuf
    float* regionA  = (float*)alloc(sizeof(float) * (size_t)NQ * DIM);
    float* qsum_c   = regionA;                       // live: qual_agg -> q_edge GEMM
    float* pre3     = regionA;                       // NN*600, live: edge_agg -> conv GEMM
    float* conv_sum = regionA + (size_t)NN * 600;    // NN*200, live: conv GEMM -> bn_apply
    float* tbuf     = conv_sum + (size_t)NN * DIM;   // NN*200, live: LRGA GEMM -> copy T
    // Region B (30e6 floats = 120 MB): q_edge_c, then cat|hbuf
    float* regionB  = (float*)alloc(sizeof(float) * (size_t)NQ * DIM);
    float* q_edge_c = regionB;                       // live: q GEMM -> edge_agg
    float* cat      = regionB;                       // NN*500, live: bn_apply -> dimred
    float* hbuf     = cat + (size_t)NN * 500;        // NN*200, live: dimred -> fuse BN (L0)
    // x_cur aliases out_x: written end of L0, last read before dimred-L1 overwrites d_out
    float* x_cur    = out_x;
    float* rel_all  = (float*)alloc(sizeof(float) * (size_t)RELALL * DIM);
    float* r_buf    = (float*)alloc(sizeof(float) * (size_t)RELROWS * DIM);
    float* wcat     = (float*)alloc(sizeof(float) * 600 * DIM);
    float* dinv0    = (float*)alloc(sizeof(float) * NN);
    float* dinv1    = (float*)alloc(sizeof(float) * NN);
    float* s1       = (float*)alloc(sizeof(float) * DIM);
    float* s2       = (float*)alloc(sizeof(float) * DIM);
    float* aa       = (float*)alloc(sizeof(float) * DIM);
    float* cc       = (float*)alloc(sizeof(float) * DIM);
    float* csUV     = (float*)alloc(sizeof(float) * 100);
    float* nfv      = (float*)alloc(sizeof(float) * 1);
    float* M50      = (float*)alloc(sizeof(float) * 2500);
    int* cnt0  = (int*)alloc(sizeof(int) * NN);
    int* ptr0  = (int*)alloc(sizeof(int) * (NN + 1));
    int* cur0  = (int*)alloc(sizeof(int) * NN);
    int* list0 = (int*)alloc(sizeof(int) * NE);
    int* cnt1  = (int*)alloc(sizeof(int) * NN);
    int* ptr1  = (int*)alloc(sizeof(int) * (NN + 1));
    int* cur1  = (int*)alloc(sizeof(int) * NN);
    int* list1 = (int*)alloc(sizeof(int) * NE);
    int* qcnt  = (int*)alloc(sizeof(int) * NE);
    int* qptr  = (int*)alloc(sizeof(int) * (NE + 1));
    int* qcur  = (int*)alloc(sizeof(int) * NE);
    int* qlist = (int*)alloc(sizeof(int) * NQ);
    int* qidx  = (int*)alloc(sizeof(int) * NE);
    int* elist = (int*)alloc(sizeof(int) * NQ);
    int* nq    = (int*)alloc(sizeof(int) * 1);
    int* partials = (int*)alloc(sizeof(int) * 1024);

    // ---- workspace-size guard: clean deterministic fail instead of GPU abort ----
    size_t needed = (size_t)(wp - (char*)d_ws);
    if (needed > ws_size) {
        long total_out = (long)out_size;
        zero_kernel<<<(int)((total_out + 255) / 256), 256, 0, stream>>>((float*)d_out, total_out);
        return;
    }

    // ---- CSR build (per call; inputs restored before every timed launch) ----
    hipMemsetAsync(cnt0, 0, sizeof(int) * NN, stream);
    hipMemsetAsync(cnt1, 0, sizeof(int) * NN, stream);
    hipMemsetAsync(qcnt, 0, sizeof(int) * NE, stream);
    hipMemsetAsync(nq, 0, sizeof(int), stream);
    hist_kernel<<<(NE + 255) / 256, 256, 0, stream>>>(ei0, NE, cnt0);
    hist_kernel<<<(NE + 255) / 256, 256, 0, stream>>>(ei1, NE, cnt1);
    hist_kernel<<<(NQ + 255) / 256, 256, 0, stream>>>(quals_edge, NQ, qcnt);
    run_exscan(cnt0, ptr0, NN, partials, stream);
    run_exscan(cnt1, ptr1, NN, partials, stream);
    run_exscan(qcnt, qptr, NE, partials, stream);
    hipMemcpyAsync(cur0, ptr0, sizeof(int) * NN, hipMemcpyDeviceToDevice, stream);
    hipMemcpyAsync(cur1, ptr1, sizeof(int) * NN, hipMemcpyDeviceToDevice, stream);
    hipMemcpyAsync(qcur, qptr, sizeof(int) * NE, hipMemcpyDeviceToDevice, stream);
    scatter_kernel<<<(NE + 255) / 256, 256, 0, stream>>>(ei0, cur0, list0, NE);
    scatter_kernel<<<(NE + 255) / 256, 256, 0, stream>>>(ei1, cur1, list1, NE);
    scatter_kernel<<<(NQ + 255) / 256, 256, 0, stream>>>(quals_edge, qcur, qlist, NQ);
    dinv_kernel<<<(NN + 255) / 256, 256, 0, stream>>>(cnt0, dinv0, NN);
    dinv_kernel<<<(NN + 255) / 256, 256, 0, stream>>>(cnt1, dinv1, NN);
    assign_kernel<<<(NE + 255) / 256, 256, 0, stream>>>(qcnt, qidx, elist, nq);

    // ---- layer loop (L=2) ----
    for (int i = 0; i < 2; ++i) {
        const float* xin  = (i == 0) ? ent_emb : x_cur;
        const float* rsrc = (i == 0) ? init_rel : r_buf;

        // rel_all = [r ; loop_rel[i]]
        hipMemcpyAsync(rel_all, rsrc, sizeof(float) * RELROWS * DIM,
                       hipMemcpyDeviceToDevice, stream);
        hipMemcpyAsync(rel_all + (long)RELROWS * DIM, loop_rel + (long)i * DIM,
                       sizeof(float) * DIM, hipMemcpyDeviceToDevice, stream);

        // qualifier aggregation into compact rows (shared by both directions)
        qual_agg_kernel<<<(NQ + 3) / 4, 256, 0, stream>>>(xin, rel_all, qptr, qlist,
                                               quals_rel, quals_ent, elist, nq, qsum_c);
        // q_edge_c = (1-alpha) * qsum_c @ w_q[i]   (dynamic M = *nq)
        launch_gemm(false, qsum_c, w_q + (long)i * DIM * DIM, q_edge_c,
                    NQ, DIM, DIM, DIM, 1.0f - ALPHA_C, nullptr, 0, 0, nq, stream);

        // per-direction aggregation into pre3 columns [0:200 | 200:400 | 400:600]
        // (pre3 overwrites qsum_c region - qsum dead after the GEMM above)
        edge_agg_kernel<<<(NN + 3) / 4, 256, 0, stream>>>(xin, rel_all, q_edge_c, qidx,
                                               ptr0, list0, ei1, edge_type, dinv0, 0,
                                               pre3, 600, 0);
        edge_agg_kernel<<<(NN + 3) / 4, 256, 0, stream>>>(xin, rel_all, q_edge_c, qidx,
                                               ptr1, list1, ei0, edge_type, dinv1, RRR,
                                               pre3, 600, 200);
        rot_loop_kernel<<<(NN + 3) / 4, 256, 0, stream>>>(xin, rel_all, pre3, 600, 400);

        // stacked conv weights: wcat = [w_in; w_out; w_loop] (600 x 200)
        hipMemcpyAsync(wcat,                 w_in   + (long)i * DIM * DIM, sizeof(float) * DIM * DIM, hipMemcpyDeviceToDevice, stream);
        hipMemcpyAsync(wcat + DIM * DIM,     w_out  + (long)i * DIM * DIM, sizeof(float) * DIM * DIM, hipMemcpyDeviceToDevice, stream);
        hipMemcpyAsync(wcat + 2 * DIM * DIM, w_loop + (long)i * DIM * DIM, sizeof(float) * DIM * DIM, hipMemcpyDeviceToDevice, stream);
        // conv_sum = pre3 @ wcat  (single K=600 GEMM)
        launch_gemm(false, pre3, wcat, conv_sum, NN, 600, DIM, DIM, 1.f, nullptr, 0, 0, nullptr, stream);

        // conv BN on conv_sum/3, relu -> x_local into cat[:,100:300]
        // (cat overwrites q_edge_c region - q_edge dead after edge_agg)
        hipMemsetAsync(s1, 0, sizeof(float) * DIM, stream);
        hipMemsetAsync(s2, 0, sizeof(float) * DIM, stream);
        bn_stats_kernel<<<512, 256, 0, stream>>>(conv_sum, 1.0f / 3.0f, 0, s1, s2);
        bn_finalize_kernel<<<1, 256, 0, stream>>>(s1, s2, conv_gamma + (long)i * DIM,
                                                  conv_beta + (long)i * DIM, aa, cc);
        bn_apply_kernel<<<NN, 256, 0, stream>>>(conv_sum, 1.0f / 3.0f, 0, aa, cc, 1,
                                                cat, 500, 100);

        // LRGA on xin: t = relu(x @ lrga_w.T + lrga_b)  (tbuf in regionA tail - safe)
        launch_gemm(true, xin, lrga_w + (long)i * 200 * DIM, tbuf,
                    NN, DIM, 200, 200, 1.f, lrga_b + (long)i * 200, 1, 0, nullptr, stream);
        hipMemsetAsync(csUV, 0, sizeof(float) * 100, stream);
        hipMemsetAsync(M50, 0, sizeof(float) * 2500, stream);
        colsum_uv_kernel<<<256, 128, 0, stream>>>(tbuf, csUV);
        nf_kernel<<<1, 64, 0, stream>>>(csUV, nfv);
        vtz_kernel<<<128, 256, 0, stream>>>(tbuf, M50);
        um_kernel<<<(NN + 255) / 256, 256, 0, stream>>>(tbuf, M50, nfv, cat);
        // cat[:,50:100] = T = t[:,150:200]
        copy_cols_kernel<<<(NN * 50 + 255) / 256, 256, 0, stream>>>(
            tbuf, DIM, 150, cat, 500, 50, NN, 50);
        // cat[:,300:500] = x
        copy_cols_kernel<<<(NN * DIM + 255) / 256, 256, 0, stream>>>(
            xin, DIM, 0, cat, 500, 300, NN, DIM);

        // dimred: h = cat @ dimred_w[i].T + dimred_b[i]
        float* hdst = (i == 0) ? hbuf : out_x;
        launch_gemm(true, cat, dimred_w + (long)i * DIM * 500, hdst,
                    NN, 500, DIM, DIM, 1.f, dimred_b + (long)i * DIM, 0, 0, nullptr, stream);

        if (i == 0) {
            // x = BN(relu(h), fuse_gamma, fuse_beta)  -> x_cur (= out_x scratch)
            hipMemsetAsync(s1, 0, sizeof(float) * DIM, stream);
            hipMemsetAsync(s2, 0, sizeof(float) * DIM, stream);
            bn_stats_kernel<<<512, 256, 0, stream>>>(hdst, 1.0f, 1, s1, s2);
            bn_finalize_kernel<<<1, 256, 0, stream>>>(s1, s2, fuse_gamma, fuse_beta, aa, cc);
            bn_apply_kernel<<<NN, 256, 0, stream>>>(hdst, 1.0f, 1, aa, cc, 0,
                                                    x_cur, DIM, 0);
        }

        // r update: (rel_all @ w_rel[i]) keep rows 0..800
        float* rdst = (i == 0) ? r_buf : out_r;
        launch_gemm(false, rel_all, w_rel + (long)i * DIM * DIM, rdst,
                    RELROWS, DIM, DIM, DIM, 1.f, nullptr, 0, 0, nullptr, stream);
    }
}